// Round 1
// baseline (400.269 us; speedup 1.0000x reference)
//
#include <hip/hip_runtime.h>
#include <stdint.h>

// MultiHeadAttention: B=4, S=2048, D_MODEL=1024, H=16, d_k=d_v=64
// Pipeline: cvt(fp32->bf16) -> QKV gemm_bt -> flash attn -> out-proj gemm_bt
// Round 1: correctness-first. bf16 MFMA 16x16x32, fp32 accum everywhere.

typedef __bf16 bf16;
typedef __bf16 bf16x8 __attribute__((ext_vector_type(8)));
typedef float f32x4 __attribute__((ext_vector_type(4)));

#define DM    1024
#define NH    16
#define SS    2048
#define BB    4
#define NTOK  8192       // B*S
#define QKVLD 3072       // qkv row stride (q|k|v)

// XOR swizzle for [row][128B] LDS tiles: spreads rows across 16B slots.
__device__ __forceinline__ int swz(int row, int byteoff) {
    return byteoff ^ ((row & 7) << 4);
}
// Vt swizzle: mixes d low+mid bits so the scattered transpose writes spread.
__device__ __forceinline__ int vswz(int d, int byteoff) {
    return byteoff ^ ((((d >> 3) ^ d) & 7) << 4);
}

__global__ void cvt_kernel(const float* __restrict__ in, bf16* __restrict__ out, int n8) {
    int i = blockIdx.x * blockDim.x + threadIdx.x;
    if (i >= n8) return;
    const float4* p = reinterpret_cast<const float4*>(in) + (size_t)i * 2;
    float4 a = p[0], b = p[1];
    bf16x8 o;
    o[0] = (bf16)a.x; o[1] = (bf16)a.y; o[2] = (bf16)a.z; o[3] = (bf16)a.w;
    o[4] = (bf16)b.x; o[5] = (bf16)b.y; o[6] = (bf16)b.z; o[7] = (bf16)b.w;
    reinterpret_cast<bf16x8*>(out)[i] = o;
}

// C[M,N] = A[M,K] * Bm[N,K]^T   (both inputs K-major, bf16; C = OT)
// 128x128 tile, BK=64, 4 waves (2x2 of 64x64), 16x16x32 bf16 MFMA.
template <typename OT>
__global__ __launch_bounds__(256) void gemm_bt(
    const bf16* __restrict__ A, const bf16* __restrict__ Bm, OT* __restrict__ C,
    int M, int N, int K)
{
    __shared__ bf16 As[128 * 64];
    __shared__ bf16 Bs[128 * 64];

    const int tn = blockIdx.x, tm = blockIdx.y;
    const int tid = threadIdx.x;
    const int lane = tid & 63, wv = tid >> 6;
    const int wr = wv >> 1, wc = wv & 1;
    const int lr = lane & 15, lg = lane >> 4;

    const f32x4 zero = {0.f, 0.f, 0.f, 0.f};
    f32x4 acc[4][4];
#pragma unroll
    for (int mi = 0; mi < 4; ++mi)
#pragma unroll
        for (int ni = 0; ni < 4; ++ni) acc[mi][ni] = zero;

    const bf16* Abase = A + (size_t)(tm * 128) * K;
    const bf16* Bbase = Bm + (size_t)(tn * 128) * K;

    for (int k0 = 0; k0 < K; k0 += 64) {
        // stage A/B tiles: 128 rows x 64 k each, reg-staged, swizzled writes
#pragma unroll
        for (int i = 0; i < 4; ++i) {
            int idx = tid + 256 * i;           // 0..1023
            int row = idx >> 3, ch = idx & 7;  // 8 chunks of 8 bf16 per row
            bf16x8 va = *reinterpret_cast<const bf16x8*>(Abase + (size_t)row * K + k0 + ch * 8);
            bf16x8 vb = *reinterpret_cast<const bf16x8*>(Bbase + (size_t)row * K + k0 + ch * 8);
            *reinterpret_cast<bf16x8*>((char*)As + swz(row, row * 128 + ch * 16)) = va;
            *reinterpret_cast<bf16x8*>((char*)Bs + swz(row, row * 128 + ch * 16)) = vb;
        }
        __syncthreads();

#pragma unroll
        for (int ks = 0; ks < 2; ++ks) {
            bf16x8 af[4], bfr[4];
#pragma unroll
            for (int mi = 0; mi < 4; ++mi) {
                int row = wr * 64 + mi * 16 + lr;
                af[mi] = *reinterpret_cast<const bf16x8*>(
                    (char*)As + swz(row, row * 128 + ks * 64 + lg * 16));
            }
#pragma unroll
            for (int ni = 0; ni < 4; ++ni) {
                int row = wc * 64 + ni * 16 + lr;
                bfr[ni] = *reinterpret_cast<const bf16x8*>(
                    (char*)Bs + swz(row, row * 128 + ks * 64 + lg * 16));
            }
#pragma unroll
            for (int mi = 0; mi < 4; ++mi)
#pragma unroll
                for (int ni = 0; ni < 4; ++ni)
                    acc[mi][ni] = __builtin_amdgcn_mfma_f32_16x16x32_bf16(
                        af[mi], bfr[ni], acc[mi][ni], 0, 0, 0);
        }
        __syncthreads();
    }

    // C/D layout: row = (lane>>4)*4 + reg, col = lane&15  [m89-verified]
#pragma unroll
    for (int mi = 0; mi < 4; ++mi)
#pragma unroll
        for (int ni = 0; ni < 4; ++ni)
#pragma unroll
            for (int r = 0; r < 4; ++r) {
                int row = tm * 128 + wr * 64 + mi * 16 + lg * 4 + r;
                int col = tn * 128 + wc * 64 + ni * 16 + lr;
                C[(size_t)row * N + col] = (OT)acc[mi][ni][r];
            }
}

// Flash attention over qkv[NTOK][3072] (cols: q|k|v, head h at h*64).
// Block = (qtile of 64 rows, b*H+h); 4 waves x 16 q-rows; KBLK=64.
__global__ __launch_bounds__(256) void attn_kernel(
    const bf16* __restrict__ qkv, const int* __restrict__ mask, bf16* __restrict__ concat)
{
    const int qt = blockIdx.x;        // 0..31
    const int bh = blockIdx.y;        // 0..63
    const int b = bh >> 4, h = bh & 15;
    const int tid = threadIdx.x;
    const int lane = tid & 63, wv = tid >> 6;
    const int lr = lane & 15, lg = lane >> 4;

    __shared__ bf16 Ks[64 * 64];       // [key][d], swizzled
    __shared__ bf16 Vt[64 * 64];       // [d][key], vswz-swizzled
    __shared__ bf16 Ps[4][16 * 64];    // per-wave P scratch [qrow][key], swizzled
    __shared__ int  kpad[64];

    const size_t tok0 = (size_t)b * SS;
    const int qrow0 = qt * 64 + wv * 16;

    // Q fragments (A-operand): lane holds q[qrow0+lr][ks*32 + lg*8 + j]
    bf16x8 aq[2];
    {
        const bf16* qp = qkv + (tok0 + qrow0 + lr) * QKVLD + h * 64 + lg * 8;
        aq[0] = *reinterpret_cast<const bf16x8*>(qp);
        aq[1] = *reinterpret_cast<const bf16x8*>(qp + 32);
    }
    int qpad[4];
#pragma unroll
    for (int r = 0; r < 4; ++r) qpad[r] = mask[tok0 + qrow0 + lg * 4 + r];

    float mrow[4], lrowv[4];
    const f32x4 zero = {0.f, 0.f, 0.f, 0.f};
    f32x4 acc[4];
#pragma unroll
    for (int r = 0; r < 4; ++r) { mrow[r] = -1e30f; lrowv[r] = 0.f; }
#pragma unroll
    for (int nf = 0; nf < 4; ++nf) acc[nf] = zero;

    for (int kb = 0; kb < SS; kb += 64) {
        __syncthreads();  // protect prev iter's Ks/Vt reads
        // --- stage K row-major + V transposed ---
#pragma unroll
        for (int i = 0; i < 2; ++i) {
            int idx = tid + 256 * i;          // 0..511
            int row = idx >> 3, ch = idx & 7; // row = key within tile
            const bf16* kp = qkv + (tok0 + kb + row) * QKVLD + 1024 + h * 64 + ch * 8;
            bf16x8 vk = *reinterpret_cast<const bf16x8*>(kp);
            *reinterpret_cast<bf16x8*>((char*)Ks + swz(row, row * 128 + ch * 16)) = vk;
            const bf16* vp = qkv + (tok0 + kb + row) * QKVLD + 2048 + h * 64 + ch * 8;
            bf16x8 vvv = *reinterpret_cast<const bf16x8*>(vp);
#pragma unroll
            for (int j = 0; j < 8; ++j) {
                int d = ch * 8 + j;
                *reinterpret_cast<bf16*>((char*)Vt + vswz(d, d * 128 + row * 2)) = vvv[j];
            }
        }
        if (tid < 64) kpad[tid] = mask[tok0 + kb + tid];
        __syncthreads();

        // --- S = Q K^T (16q x 64key), D rows = lg*4+r, col = key = nf*16+lr ---
        float sv[4][4];
#pragma unroll
        for (int nf = 0; nf < 4; ++nf) {
            f32x4 s = zero;
#pragma unroll
            for (int ks = 0; ks < 2; ++ks) {
                int row = nf * 16 + lr;  // key row in Ks
                bf16x8 bk = *reinterpret_cast<const bf16x8*>(
                    (char*)Ks + swz(row, row * 128 + ks * 64 + lg * 16));
                s = __builtin_amdgcn_mfma_f32_16x16x32_bf16(aq[ks], bk, s, 0, 0, 0);
            }
#pragma unroll
            for (int r = 0; r < 4; ++r) sv[nf][r] = s[r];
        }
        // scale + mask (1 = pad)
#pragma unroll
        for (int nf = 0; nf < 4; ++nf) {
            int kinv = kpad[nf * 16 + lr];
#pragma unroll
            for (int r = 0; r < 4; ++r) {
                float v = sv[nf][r] * 0.125f;
                sv[nf][r] = (kinv | qpad[r]) ? -1e9f : v;
            }
        }
        // --- online softmax: row reductions across the 16 col-lanes ---
        float pm[4];
#pragma unroll
        for (int r = 0; r < 4; ++r)
            pm[r] = fmaxf(fmaxf(sv[0][r], sv[1][r]), fmaxf(sv[2][r], sv[3][r]));
#pragma unroll
        for (int mgo = 1; mgo < 16; mgo <<= 1)
#pragma unroll
            for (int r = 0; r < 4; ++r) pm[r] = fmaxf(pm[r], __shfl_xor(pm[r], mgo));

        float sc[4];
#pragma unroll
        for (int r = 0; r < 4; ++r) {
            float mnew = fmaxf(mrow[r], pm[r]);
            sc[r] = __expf(mrow[r] - mnew);
            mrow[r] = mnew;
        }
        float p[4][4], psum[4];
#pragma unroll
        for (int r = 0; r < 4; ++r) psum[r] = 0.f;
#pragma unroll
        for (int nf = 0; nf < 4; ++nf)
#pragma unroll
            for (int r = 0; r < 4; ++r) {
                p[nf][r] = __expf(sv[nf][r] - mrow[r]);
                psum[r] += p[nf][r];
            }
#pragma unroll
        for (int mgo = 1; mgo < 16; mgo <<= 1)
#pragma unroll
            for (int r = 0; r < 4; ++r) psum[r] += __shfl_xor(psum[r], mgo);
#pragma unroll
        for (int r = 0; r < 4; ++r) lrowv[r] = lrowv[r] * sc[r] + psum[r];
#pragma unroll
        for (int nf = 0; nf < 4; ++nf)
#pragma unroll
            for (int r = 0; r < 4; ++r) acc[nf][r] *= sc[r];

        // --- P (D-layout) -> wave-private LDS -> A-layout fragments ---
#pragma unroll
        for (int nf = 0; nf < 4; ++nf)
#pragma unroll
            for (int r = 0; r < 4; ++r) {
                int qr = lg * 4 + r, key = nf * 16 + lr;
                *reinterpret_cast<bf16*>(
                    (char*)Ps[wv] + swz(qr, qr * 128 + key * 2)) = (bf16)p[nf][r];
            }
        // --- PV: acc[nf] += P[16q x 64k] * V[64k x 64d] ---
#pragma unroll
        for (int ks = 0; ks < 2; ++ks) {
            bf16x8 ap = *reinterpret_cast<const bf16x8*>(
                (char*)Ps[wv] + swz(lr, lr * 128 + ks * 64 + lg * 16));
#pragma unroll
            for (int nf = 0; nf < 4; ++nf) {
                int rowv = nf * 16 + lr;  // d row in Vt
                bf16x8 bv = *reinterpret_cast<const bf16x8*>(
                    (char*)Vt + vswz(rowv, rowv * 128 + ks * 64 + lg * 16));
                acc[nf] = __builtin_amdgcn_mfma_f32_16x16x32_bf16(ap, bv, acc[nf], 0, 0, 0);
            }
        }
    }

    // epilogue: normalize, write concat[token][h*64 + d] (bf16)
#pragma unroll
    for (int r = 0; r < 4; ++r) {
        float inv = 1.0f / lrowv[r];
        int row = qrow0 + lg * 4 + r;
#pragma unroll
        for (int nf = 0; nf < 4; ++nf) {
            int col = h * 64 + nf * 16 + lr;
            concat[(tok0 + row) * DM + col] = (bf16)(acc[nf][r] * inv);
        }
    }
}

extern "C" void kernel_launch(void* const* d_in, const int* in_sizes, int n_in,
                              void* d_out, int out_size, void* d_ws, size_t ws_size,
                              hipStream_t stream)
{
    const float* x  = (const float*)d_in[0];
    const int* mask = (const int*)d_in[1];
    const float* Wq = (const float*)d_in[2];
    const float* Wk = (const float*)d_in[3];
    const float* Wv = (const float*)d_in[4];
    const float* Wo = (const float*)d_in[5];
    float* out = (float*)d_out;

    // workspace layout (72 MiB total)
    char* ws = (char*)d_ws;
    bf16* xb     = (bf16*)(ws);                                    // [8192][1024] 16 MiB
    bf16* wqkv   = (bf16*)(ws + (16ull << 20));                    // [3072][1024]  6 MiB
    bf16* wob    = (bf16*)(ws + (16ull << 20) + (6ull << 20));     // [1024][1024]  2 MiB
    bf16* qkv    = (bf16*)(ws + (24ull << 20));                    // [8192][3072] 48 MiB
    bf16* concat = xb;  // xb is dead after the QKV GEMM — reuse as concat

    cvt_kernel<<<dim3((NTOK * DM / 8) / 256), 256, 0, stream>>>(x, xb, NTOK * DM / 8);
    cvt_kernel<<<dim3((DM * DM / 8) / 256), 256, 0, stream>>>(Wq, wqkv, DM * DM / 8);
    cvt_kernel<<<dim3((DM * DM / 8) / 256), 256, 0, stream>>>(Wk, wqkv + DM * DM, DM * DM / 8);
    cvt_kernel<<<dim3((DM * DM / 8) / 256), 256, 0, stream>>>(Wv, wqkv + 2 * DM * DM, DM * DM / 8);
    cvt_kernel<<<dim3((DM * DM / 8) / 256), 256, 0, stream>>>(Wo, wob, DM * DM / 8);

    // QKV projection: [8192,3072] = xb[8192,1024] @ wqkv[3072,1024]^T
    gemm_bt<bf16><<<dim3(QKVLD / 128, NTOK / 128), 256, 0, stream>>>(
        xb, wqkv, qkv, NTOK, QKVLD, DM);

    // attention -> concat[8192][1024]
    attn_kernel<<<dim3(SS / 64, BB * NH), 256, 0, stream>>>(qkv, mask, concat);

    // output projection: out[8192,1024] = concat @ wob^T  (fp32 out)
    gemm_bt<float><<<dim3(DM / 128, NTOK / 128), 256, 0, stream>>>(
        concat, wob, out, NTOK, DM, DM);
}

// Round 2
// 274.441 us; speedup vs baseline: 1.4585x; 1.4585x over previous
//
#include <hip/hip_runtime.h>
#include <stdint.h>

// MultiHeadAttention: B=4, S=2048, D_MODEL=1024, H=16, d_k=d_v=64
// Round 2: m214-style swapped-QK^T 32x32 attention, in-register softmax,
// cvt_pk+permlane32_swap P re-fragmentation, pre-transposed V, T14 prefetch.

typedef __bf16 bf16;
typedef __bf16 bf16x8 __attribute__((ext_vector_type(8)));
typedef __bf16 bf16x4 __attribute__((ext_vector_type(4)));
typedef float f32x4 __attribute__((ext_vector_type(4)));
typedef float f32x16 __attribute__((ext_vector_type(16)));

#define DM    1024
#define NH    16
#define SS    2048
#define BB    4
#define NTOK  8192

// XOR swizzle for [row][128B] LDS tiles: spreads rows across 16B slots.
__device__ __forceinline__ int swz(int row, int byteoff) {
    return byteoff ^ ((row & 7) << 4);
}

__device__ __forceinline__ uint32_t cvtpk(float lo, float hi_) {
    uint32_t r;
    asm("v_cvt_pk_bf16_f32 %0, %1, %2" : "=v"(r) : "v"(lo), "v"(hi_));
    return r;
}

__global__ void cvt_kernel(const float* __restrict__ in, bf16* __restrict__ out, int n8) {
    int i = blockIdx.x * blockDim.x + threadIdx.x;
    if (i >= n8) return;
    const float4* p = reinterpret_cast<const float4*>(in) + (size_t)i * 2;
    float4 a = p[0], b = p[1];
    bf16x8 o;
    o[0] = (bf16)a.x; o[1] = (bf16)a.y; o[2] = (bf16)a.z; o[3] = (bf16)a.w;
    o[4] = (bf16)b.x; o[5] = (bf16)b.y; o[6] = (bf16)b.z; o[7] = (bf16)b.w;
    reinterpret_cast<bf16x8*>(out)[i] = o;
}

// C[M,N] = A[M,K] * Bm[N,K]^T   (both inputs K-major, bf16; C = OT)
// 128x128 tile, BK=64, 4 waves (2x2 of 64x64), 16x16x32 bf16 MFMA.
template <typename OT>
__global__ __launch_bounds__(256) void gemm_bt(
    const bf16* __restrict__ A, const bf16* __restrict__ Bm, OT* __restrict__ C,
    int M, int N, int K)
{
    __shared__ bf16 As[128 * 64];
    __shared__ bf16 Bs[128 * 64];

    const int tn = blockIdx.x, tm = blockIdx.y;
    const int tid = threadIdx.x;
    const int lane = tid & 63, wv = tid >> 6;
    const int wr = wv >> 1, wc = wv & 1;
    const int lr = lane & 15, lg = lane >> 4;

    const f32x4 zero = {0.f, 0.f, 0.f, 0.f};
    f32x4 acc[4][4];
#pragma unroll
    for (int mi = 0; mi < 4; ++mi)
#pragma unroll
        for (int ni = 0; ni < 4; ++ni) acc[mi][ni] = zero;

    const bf16* Abase = A + (size_t)(tm * 128) * K;
    const bf16* Bbase = Bm + (size_t)(tn * 128) * K;

    for (int k0 = 0; k0 < K; k0 += 64) {
#pragma unroll
        for (int i = 0; i < 4; ++i) {
            int idx = tid + 256 * i;
            int row = idx >> 3, ch = idx & 7;
            bf16x8 va = *reinterpret_cast<const bf16x8*>(Abase + (size_t)row * K + k0 + ch * 8);
            bf16x8 vb = *reinterpret_cast<const bf16x8*>(Bbase + (size_t)row * K + k0 + ch * 8);
            *reinterpret_cast<bf16x8*>((char*)As + swz(row, row * 128 + ch * 16)) = va;
            *reinterpret_cast<bf16x8*>((char*)Bs + swz(row, row * 128 + ch * 16)) = vb;
        }
        __syncthreads();

#pragma unroll
        for (int ks = 0; ks < 2; ++ks) {
            bf16x8 af[4], bfr[4];
#pragma unroll
            for (int mi = 0; mi < 4; ++mi) {
                int row = wr * 64 + mi * 16 + lr;
                af[mi] = *reinterpret_cast<const bf16x8*>(
                    (char*)As + swz(row, row * 128 + ks * 64 + lg * 16));
            }
#pragma unroll
            for (int ni = 0; ni < 4; ++ni) {
                int row = wc * 64 + ni * 16 + lr;
                bfr[ni] = *reinterpret_cast<const bf16x8*>(
                    (char*)Bs + swz(row, row * 128 + ks * 64 + lg * 16));
            }
#pragma unroll
            for (int mi = 0; mi < 4; ++mi)
#pragma unroll
                for (int ni = 0; ni < 4; ++ni)
                    acc[mi][ni] = __builtin_amdgcn_mfma_f32_16x16x32_bf16(
                        af[mi], bfr[ni], acc[mi][ni], 0, 0, 0);
        }
        __syncthreads();
    }

#pragma unroll
    for (int mi = 0; mi < 4; ++mi)
#pragma unroll
        for (int ni = 0; ni < 4; ++ni)
#pragma unroll
            for (int r = 0; r < 4; ++r) {
                int row = tm * 128 + wr * 64 + mi * 16 + lg * 4 + r;
                int col = tn * 128 + wc * 64 + ni * 16 + lr;
                C[(size_t)row * N + col] = (OT)acc[mi][ni][r];
            }
}

// Transpose V: vb[token][1024] head-cols -> vT[(bh*64+d)][s]
__global__ __launch_bounds__(256) void vtrans_kernel(
    const bf16* __restrict__ vb, bf16* __restrict__ vT)
{
    const int st = blockIdx.x, bh = blockIdx.y;
    const int b = bh >> 4, h = bh & 15;
    const int tid = threadIdx.x;
    __shared__ bf16 T[64 * 64];
#pragma unroll
    for (int i = 0; i < 2; ++i) {
        int idx = tid + 256 * i;
        int s = idx >> 3, ch = idx & 7;
        bf16x8 v = *reinterpret_cast<const bf16x8*>(
            vb + (size_t)(b * SS + st * 64 + s) * DM + h * 64 + ch * 8);
        *reinterpret_cast<bf16x8*>((char*)T + swz(s, s * 128 + ch * 16)) = v;
    }
    __syncthreads();
#pragma unroll
    for (int i = 0; i < 2; ++i) {
        int idx = tid + 256 * i;
        int d = idx >> 3, ch = idx & 7;
        bf16x8 o;
#pragma unroll
        for (int j = 0; j < 8; ++j) {
            int s = ch * 8 + j;
            o[j] = *reinterpret_cast<const bf16*>((char*)T + swz(s, s * 128 + d * 2));
        }
        *reinterpret_cast<bf16x8*>(vT + ((size_t)bh * 64 + d) * SS + st * 64 + ch * 8) = o;
    }
}

// Flash attention, swapped-QK^T 32x32 structure.
// Block = (128 q rows, bh); 4 waves x 32 q-rows; KVBLK=64.
// Per lane: q = lane&31 for softmax stats AND the O^T output column.
__global__ __launch_bounds__(256) void attn_kernel(
    const bf16* __restrict__ qmat, const bf16* __restrict__ kmat,
    const bf16* __restrict__ vT, const int* __restrict__ mask,
    bf16* __restrict__ concat)
{
    const int qt = blockIdx.x;   // 0..15
    const int bh = blockIdx.y;   // 0..63
    const int b = bh >> 4, h = bh & 15;
    const int tid = threadIdx.x;
    const int lane = tid & 63, wv = tid >> 6;
    const int lq = lane & 31, hi = lane >> 5;

    __shared__ bf16 Ks[64 * 64];   // [key][d]   swizzled
    __shared__ bf16 Vs[64 * 64];   // [d][key]   swizzled (from vT)

    const size_t tok0 = (size_t)b * SS;
    const int qrow0 = qt * 128 + wv * 32;

    // Q fragments (B-operand), scaled by 1/8, zeroed for padded q rows.
    const int qpad = mask[tok0 + qrow0 + lq];
    bf16x8 qf[4];
    {
        const bf16* qp = qmat + (tok0 + qrow0 + lq) * DM + h * 64 + hi * 8;
#pragma unroll
        for (int ks = 0; ks < 4; ++ks) {
            bf16x8 v = *reinterpret_cast<const bf16x8*>(qp + ks * 16);
#pragma unroll
            for (int j = 0; j < 8; ++j)
                v[j] = qpad ? (bf16)0.f : (bf16)((float)v[j] * 0.125f);
            qf[ks] = v;
        }
    }

    float mrow = -3e38f, lrow = 0.f;
    f32x16 o[2];
#pragma unroll
    for (int e = 0; e < 16; ++e) { o[0][e] = 0.f; o[1][e] = 0.f; }

    // T14 prefetch: tile 0 staged to regs
    bf16x8 stK[2], stV[2];
    {
#pragma unroll
        for (int i = 0; i < 2; ++i) {
            int idx = tid + 256 * i;
            int row = idx >> 3, ch = idx & 7;
            stK[i] = *reinterpret_cast<const bf16x8*>(
                kmat + (tok0 + row) * DM + h * 64 + ch * 8);
            stV[i] = *reinterpret_cast<const bf16x8*>(
                vT + ((size_t)bh * 64 + row) * SS + ch * 8);
        }
    }
    int mval = mask[tok0 + lane];

    for (int kt = 0; kt < SS; kt += 64) {
        __syncthreads();   // prior tile's LDS reads complete
#pragma unroll
        for (int i = 0; i < 2; ++i) {
            int idx = tid + 256 * i;
            int row = idx >> 3, ch = idx & 7;
            *reinterpret_cast<bf16x8*>((char*)Ks + swz(row, row * 128 + ch * 16)) = stK[i];
            *reinterpret_cast<bf16x8*>((char*)Vs + swz(row, row * 128 + ch * 16)) = stV[i];
        }
        unsigned long long km = __ballot(mval != 0);
        if (kt + 64 < SS) {   // issue next-tile global loads (hidden under compute)
#pragma unroll
            for (int i = 0; i < 2; ++i) {
                int idx = tid + 256 * i;
                int row = idx >> 3, ch = idx & 7;
                stK[i] = *reinterpret_cast<const bf16x8*>(
                    kmat + (tok0 + kt + 64 + row) * DM + h * 64 + ch * 8);
                stV[i] = *reinterpret_cast<const bf16x8*>(
                    vT + ((size_t)bh * 64 + row) * SS + kt + 64 + ch * 8);
            }
            mval = mask[tok0 + kt + 64 + lane];
        }
        __syncthreads();   // staged tile visible

        // per-lane key-pad bit masks (key bit index = 4*hi + (e&3) + 8*(e>>2))
        uint32_t vmh0 = (uint32_t)km, vmh1 = (uint32_t)(km >> 32);
        if (qpad) { vmh0 = 0; vmh1 = 0; }   // padded q: keep all p=1 (uniform)
        vmh0 >>= 4 * hi; vmh1 >>= 4 * hi;

        // S^T[key][q] = K . Q^T  (keys in 2 halves of 32)
        f32x16 s0, s1;
#pragma unroll
        for (int e = 0; e < 16; ++e) { s0[e] = 0.f; s1[e] = 0.f; }
#pragma unroll
        for (int ks = 0; ks < 4; ++ks) {
            int r0 = lq, r1 = 32 + lq;
            bf16x8 k0 = *reinterpret_cast<const bf16x8*>(
                (char*)Ks + swz(r0, r0 * 128 + ks * 32 + hi * 16));
            bf16x8 k1 = *reinterpret_cast<const bf16x8*>(
                (char*)Ks + swz(r1, r1 * 128 + ks * 32 + hi * 16));
            s0 = __builtin_amdgcn_mfma_f32_32x32x16_bf16(k0, qf[ks], s0, 0, 0, 0);
            s1 = __builtin_amdgcn_mfma_f32_32x32x16_bf16(k1, qf[ks], s1, 0, 0, 0);
        }

        // online softmax (q = lane&31): in-lane max over 32 + cross-half swap
        float pm = s0[0];
#pragma unroll
        for (int e = 1; e < 16; ++e) pm = fmaxf(pm, s0[e]);
#pragma unroll
        for (int e = 0; e < 16; ++e) pm = fmaxf(pm, s1[e]);
        pm = fmaxf(pm, __shfl_xor(pm, 32));
        float mnew = fmaxf(mrow, pm);
        float scf = __expf(mrow - mnew);
        mrow = mnew;

        float psum = 0.f;
        float p0[16], p1[16];
#pragma unroll
        for (int e = 0; e < 16; ++e) {
            int sh = (e & 3) + 8 * (e >> 2);
            float a = __expf(s0[e] - mrow);
            a = ((vmh0 >> sh) & 1) ? 0.f : a;
            p0[e] = a; psum += a;
            float c = __expf(s1[e] - mrow);
            c = ((vmh1 >> sh) & 1) ? 0.f : c;
            p1[e] = c; psum += c;
        }
        psum += __shfl_xor(psum, 32);
        lrow = lrow * scf + psum;
#pragma unroll
        for (int e = 0; e < 16; ++e) { o[0][e] *= scf; o[1][e] *= scf; }

        // P -> bf16 B-fragments (cvt_pk + permlane32_swap), PV: O^T += V^T P^T^T
#pragma unroll
        for (int kk = 0; kk < 4; ++kk) {
            const float* pp = (kk < 2) ? p0 : p1;
            const int ks2 = kk & 1;
            uint32_t c0 = cvtpk(pp[8 * ks2 + 0], pp[8 * ks2 + 1]);
            uint32_t c1 = cvtpk(pp[8 * ks2 + 2], pp[8 * ks2 + 3]);
            uint32_t c2 = cvtpk(pp[8 * ks2 + 4], pp[8 * ks2 + 5]);
            uint32_t c3 = cvtpk(pp[8 * ks2 + 6], pp[8 * ks2 + 7]);
            asm("v_permlane32_swap_b32 %0, %1" : "+v"(c0), "+v"(c2));
            asm("v_permlane32_swap_b32 %0, %1" : "+v"(c1), "+v"(c3));
            union { uint32_t u[4]; bf16x8 v; } pu;
            pu.u[0] = c0; pu.u[1] = c1; pu.u[2] = c2; pu.u[3] = c3;
            bf16x8 pa = pu.v;
#pragma unroll
            for (int onf = 0; onf < 2; ++onf) {
                int row = onf * 32 + lq;
                bf16x8 vf = *reinterpret_cast<const bf16x8*>(
                    (char*)Vs + swz(row, row * 128 + kk * 32 + hi * 16));
                o[onf] = __builtin_amdgcn_mfma_f32_32x32x16_bf16(vf, pa, o[onf], 0, 0, 0);
            }
        }
    }

    // epilogue: O^T rows d = onf*32 + 4*hi + 8*g + r, col q = lane&31
    float inv = 1.0f / lrow;
#pragma unroll
    for (int onf = 0; onf < 2; ++onf)
#pragma unroll
        for (int g = 0; g < 4; ++g) {
            bf16x4 w;
#pragma unroll
            for (int r = 0; r < 4; ++r) w[r] = (bf16)(o[onf][g * 4 + r] * inv);
            int d0 = onf * 32 + 4 * hi + 8 * g;
            *reinterpret_cast<bf16x4*>(
                concat + (tok0 + qrow0 + lq) * DM + h * 64 + d0) = w;
        }
}

extern "C" void kernel_launch(void* const* d_in, const int* in_sizes, int n_in,
                              void* d_out, int out_size, void* d_ws, size_t ws_size,
                              hipStream_t stream)
{
    const float* x  = (const float*)d_in[0];
    const int* mask = (const int*)d_in[1];
    const float* Wq = (const float*)d_in[2];
    const float* Wk = (const float*)d_in[3];
    const float* Wv = (const float*)d_in[4];
    const float* Wv_ = Wv; (void)Wv_;
    const float* Wo = (const float*)d_in[5];
    float* out = (float*)d_out;

    // workspace layout (72 MiB), time-multiplexed:
    //  [0,16)  xb (bf16 x)      -> vT after QKV gemms (xb dead)
    //  [16,18) wq  [18,20) wk  [20,22) wv  [22,24) wob
    //  [24,40) qbuf  [40,56) kbuf  [56,72) vbuf -> concat after vtrans
    char* ws = (char*)d_ws;
    bf16* xb    = (bf16*)(ws);
    bf16* wq    = (bf16*)(ws + (16ull << 20));
    bf16* wk    = (bf16*)(ws + (18ull << 20));
    bf16* wv    = (bf16*)(ws + (20ull << 20));
    bf16* wob   = (bf16*)(ws + (22ull << 20));
    bf16* qbuf  = (bf16*)(ws + (24ull << 20));
    bf16* kbuf  = (bf16*)(ws + (40ull << 20));
    bf16* vbuf  = (bf16*)(ws + (56ull << 20));
    bf16* vT    = xb;     // aliases xb (dead after QKV gemms)
    bf16* concat = vbuf;  // aliases vbuf (dead after vtrans)

    cvt_kernel<<<dim3((NTOK * DM / 8) / 256), 256, 0, stream>>>(x, xb, NTOK * DM / 8);
    cvt_kernel<<<dim3((DM * DM / 8) / 256), 256, 0, stream>>>(Wq, wq, DM * DM / 8);
    cvt_kernel<<<dim3((DM * DM / 8) / 256), 256, 0, stream>>>(Wk, wk, DM * DM / 8);
    cvt_kernel<<<dim3((DM * DM / 8) / 256), 256, 0, stream>>>(Wv, wv, DM * DM / 8);
    cvt_kernel<<<dim3((DM * DM / 8) / 256), 256, 0, stream>>>(Wo, wob, DM * DM / 8);

    gemm_bt<bf16><<<dim3(DM / 128, NTOK / 128), 256, 0, stream>>>(xb, wq, qbuf, NTOK, DM, DM);
    gemm_bt<bf16><<<dim3(DM / 128, NTOK / 128), 256, 0, stream>>>(xb, wk, kbuf, NTOK, DM, DM);
    gemm_bt<bf16><<<dim3(DM / 128, NTOK / 128), 256, 0, stream>>>(xb, wv, vbuf, NTOK, DM, DM);

    vtrans_kernel<<<dim3(SS / 64, BB * NH), 256, 0, stream>>>(vbuf, vT);

    attn_kernel<<<dim3(SS / 128, BB * NH), 256, 0, stream>>>(qbuf, kbuf, vT, mask, concat);

    gemm_bt<float><<<dim3(DM / 128, NTOK / 128), 256, 0, stream>>>(concat, wob, out, NTOK, DM, DM);
}

// Round 3
// 262.833 us; speedup vs baseline: 1.5229x; 1.0442x over previous
//
#include <hip/hip_runtime.h>
#include <stdint.h>

// MultiHeadAttention: B=4, S=2048, D_MODEL=1024, H=16, d_k=d_v=64
// Round 3: attn VALU cuts (bias-in-MFMA-C mask, exp2 domain, defer-max) +
// GEMM staging via global_load_lds width-16 (m97 structure).

typedef __bf16 bf16;
typedef __bf16 bf16x8 __attribute__((ext_vector_type(8)));
typedef __bf16 bf16x4 __attribute__((ext_vector_type(4)));
typedef float f32x4 __attribute__((ext_vector_type(4)));
typedef float f32x16 __attribute__((ext_vector_type(16)));

#define DM    1024
#define NH    16
#define SS    2048
#define BB    4
#define NTOK  8192
#define LOG2E_DIV8 0.18033688011112042f   // log2(e)/8: QK scale folded into Q, exp2 domain

// XOR swizzle for [row][128B] LDS tiles.
__device__ __forceinline__ int swz(int row, int byteoff) {
    return byteoff ^ ((row & 7) << 4);
}
__device__ __forceinline__ float fexp2(float x) {
    float r; asm("v_exp_f32 %0, %1" : "=v"(r) : "v"(x)); return r;
}
__device__ __forceinline__ uint32_t cvtpk(float lo, float hi_) {
    uint32_t r; asm("v_cvt_pk_bf16_f32 %0, %1, %2" : "=v"(r) : "v"(lo), "v"(hi_)); return r;
}
// async global->LDS, 16B per lane (dest must be linear: base + lane*16)
__device__ __forceinline__ void gload_lds16(const void* g, void* l) {
    __builtin_amdgcn_global_load_lds(
        (const __attribute__((address_space(1))) uint32_t*)g,
        (__attribute__((address_space(3))) uint32_t*)l, 16, 0, 0);
}

__global__ void cvt_kernel(const float* __restrict__ in, bf16* __restrict__ out, int n8) {
    int i = blockIdx.x * blockDim.x + threadIdx.x;
    if (i >= n8) return;
    const float4* p = reinterpret_cast<const float4*>(in) + (size_t)i * 2;
    float4 a = p[0], b = p[1];
    bf16x8 o;
    o[0] = (bf16)a.x; o[1] = (bf16)a.y; o[2] = (bf16)a.z; o[3] = (bf16)a.w;
    o[4] = (bf16)b.x; o[5] = (bf16)b.y; o[6] = (bf16)b.z; o[7] = (bf16)b.w;
    reinterpret_cast<bf16x8*>(out)[i] = o;
}

// bias[b5][kt][hs][hi][e]: -inf where key padded, 0 otherwise; slice b=4 all zero
// (used by padded-q lanes). acc element e of s_{hs} maps to key = 32*hs + 4*hi + 8*(e>>2) + (e&3).
__global__ void biasprep_kernel(const int* __restrict__ mask, float* __restrict__ bias) {
    int idx = blockIdx.x * blockDim.x + threadIdx.x;
    if (idx >= 5 * 2048) return;
    int e = idx & 15, hi = (idx >> 4) & 1, hs = (idx >> 5) & 1;
    int kt = (idx >> 6) & 31, b = idx >> 11;
    int key = 32 * hs + 4 * hi + 8 * (e >> 2) + (e & 3);
    float v = 0.f;
    if (b < 4 && mask[b * SS + kt * 64 + key]) v = -__builtin_inff();
    bias[idx] = v;
}

// C[M,N] = A[M,K] * Bm[N,K]^T. 128x128 tile, BK=64, 4 waves, 16x16x32 MFMA.
// Staging: global_load_lds w=16, linear LDS dest, pre-swizzled global source.
template <typename OT>
__global__ __launch_bounds__(256) void gemm_bt(
    const bf16* __restrict__ A, const bf16* __restrict__ Bm, OT* __restrict__ C,
    int M, int N, int K)
{
    __shared__ bf16 As[128 * 64];
    __shared__ bf16 Bs[128 * 64];

    const int tn = blockIdx.x, tm = blockIdx.y;
    const int tid = threadIdx.x;
    const int lane = tid & 63, wv = tid >> 6;
    const int wr = wv >> 1, wc = wv & 1;
    const int lr = lane & 15, lg = lane >> 4;

    const f32x4 zero = {0.f, 0.f, 0.f, 0.f};
    f32x4 acc[4][4];
#pragma unroll
    for (int mi = 0; mi < 4; ++mi)
#pragma unroll
        for (int ni = 0; ni < 4; ++ni) acc[mi][ni] = zero;

    const char* Abase = (const char*)(A + (size_t)(tm * 128) * K);
    const char* Bbase = (const char*)(Bm + (size_t)(tn * 128) * K);

    for (int k0 = 0; k0 < K; k0 += 64) {
#pragma unroll
        for (int i = 0; i < 4; ++i) {
            int idx = tid + 256 * i;
            int row = idx >> 3, ch = idx & 7;
            int gcol = (ch * 16) ^ ((row & 7) << 4);   // pre-swizzled source column
            size_t roff = (size_t)row * (K * 2) + k0 * 2 + gcol;
            gload_lds16(Abase + roff, (char*)As + idx * 16);
            gload_lds16(Bbase + roff, (char*)Bs + idx * 16);
        }
        __syncthreads();   // compiler drains vmcnt(0) before barrier

#pragma unroll
        for (int ks = 0; ks < 2; ++ks) {
            bf16x8 af[4], bfr[4];
#pragma unroll
            for (int mi = 0; mi < 4; ++mi) {
                int row = wr * 64 + mi * 16 + lr;
                af[mi] = *reinterpret_cast<const bf16x8*>(
                    (char*)As + swz(row, row * 128 + ks * 64 + lg * 16));
            }
#pragma unroll
            for (int ni = 0; ni < 4; ++ni) {
                int row = wc * 64 + ni * 16 + lr;
                bfr[ni] = *reinterpret_cast<const bf16x8*>(
                    (char*)Bs + swz(row, row * 128 + ks * 64 + lg * 16));
            }
#pragma unroll
            for (int mi = 0; mi < 4; ++mi)
#pragma unroll
                for (int ni = 0; ni < 4; ++ni)
                    acc[mi][ni] = __builtin_amdgcn_mfma_f32_16x16x32_bf16(
                        af[mi], bfr[ni], acc[mi][ni], 0, 0, 0);
        }
        __syncthreads();
    }

#pragma unroll
    for (int mi = 0; mi < 4; ++mi)
#pragma unroll
        for (int ni = 0; ni < 4; ++ni)
#pragma unroll
            for (int r = 0; r < 4; ++r) {
                int row = tm * 128 + wr * 64 + mi * 16 + lg * 4 + r;
                int col = tn * 128 + wc * 64 + ni * 16 + lr;
                C[(size_t)row * N + col] = (OT)acc[mi][ni][r];
            }
}

// Transpose V: vb[token][1024] head-cols -> vT[(bh*64+d)][s]
__global__ __launch_bounds__(256) void vtrans_kernel(
    const bf16* __restrict__ vb, bf16* __restrict__ vT)
{
    const int st = blockIdx.x, bh = blockIdx.y;
    const int b = bh >> 4, h = bh & 15;
    const int tid = threadIdx.x;
    __shared__ bf16 T[64 * 64];
#pragma unroll
    for (int i = 0; i < 2; ++i) {
        int idx = tid + 256 * i;
        int s = idx >> 3, ch = idx & 7;
        bf16x8 v = *reinterpret_cast<const bf16x8*>(
            vb + (size_t)(b * SS + st * 64 + s) * DM + h * 64 + ch * 8);
        *reinterpret_cast<bf16x8*>((char*)T + swz(s, s * 128 + ch * 16)) = v;
    }
    __syncthreads();
#pragma unroll
    for (int i = 0; i < 2; ++i) {
        int idx = tid + 256 * i;
        int d = idx >> 3, ch = idx & 7;
        bf16x8 o;
#pragma unroll
        for (int j = 0; j < 8; ++j) {
            int s = ch * 8 + j;
            o[j] = *reinterpret_cast<const bf16*>((char*)T + swz(s, s * 128 + d * 2));
        }
        *reinterpret_cast<bf16x8*>(vT + ((size_t)bh * 64 + d) * SS + st * 64 + ch * 8) = o;
    }
}

// Flash attention, swapped-QK^T 32x32; mask via bias-in-C, exp2 domain, defer-max.
__global__ __launch_bounds__(256) void attn_kernel(
    const bf16* __restrict__ qmat, const bf16* __restrict__ kmat,
    const bf16* __restrict__ vT, const int* __restrict__ mask,
    const float* __restrict__ bias, bf16* __restrict__ concat)
{
    const int qt = blockIdx.x;   // 0..15
    const int bh = blockIdx.y;   // 0..63
    const int b = bh >> 4, h = bh & 15;
    const int tid = threadIdx.x;
    const int lane = tid & 63, wv = tid >> 6;
    const int lq = lane & 31, hi = lane >> 5;

    __shared__ bf16 Ks[64 * 64];   // [key][d]  swizzled
    __shared__ bf16 Vs[64 * 64];   // [d][key]  swizzled (from vT)

    const size_t tok0 = (size_t)b * SS;
    const int qrow0 = qt * 128 + wv * 32;

    // Q fragments (B-operand), scale log2e/8 folded in, zeroed for padded q.
    const int qpad = mask[tok0 + qrow0 + lq];
    bf16x8 qf[4];
    {
        const bf16* qp = qmat + (tok0 + qrow0 + lq) * DM + h * 64 + hi * 8;
#pragma unroll
        for (int ks = 0; ks < 4; ++ks) {
            bf16x8 v = *reinterpret_cast<const bf16x8*>(qp + ks * 16);
#pragma unroll
            for (int j = 0; j < 8; ++j)
                v[j] = qpad ? (bf16)0.f : (bf16)((float)v[j] * LOG2E_DIV8);
            qf[ks] = v;
        }
    }
    // padded-q lanes read the all-zero b=4 slice (uniform softmax over all keys)
    const float* bbase = bias + (size_t)(qpad ? 4 : b) * 2048 + hi * 16;

    float mrow = -3e38f, lrow = 0.f;
    f32x16 oA, oB;
#pragma unroll
    for (int e = 0; e < 16; ++e) { oA[e] = 0.f; oB[e] = 0.f; }

    // hoisted LDS read bases (rows lq and 32+lq share (row&7))
    const char* kR0 = (char*)Ks + lq * 128;
    const char* kR1 = (char*)Ks + (32 + lq) * 128;
    const char* vR0 = (char*)Vs + lq * 128;
    const char* vR1 = (char*)Vs + (32 + lq) * 128;
    const int cx = (hi * 16) ^ ((lq & 7) << 4);

    // T14 prefetch: tile 0 -> regs
    bf16x8 stK[2], stV[2];
#pragma unroll
    for (int i = 0; i < 2; ++i) {
        int idx = tid + 256 * i;
        int row = idx >> 3, ch = idx & 7;
        stK[i] = *reinterpret_cast<const bf16x8*>(kmat + (tok0 + row) * DM + h * 64 + ch * 8);
        stV[i] = *reinterpret_cast<const bf16x8*>(vT + ((size_t)bh * 64 + row) * SS + ch * 8);
    }

    for (int kt = 0; kt < 32; ++kt) {
        __syncthreads();   // prior tile's LDS reads complete
#pragma unroll
        for (int i = 0; i < 2; ++i) {
            int idx = tid + 256 * i;
            int row = idx >> 3, ch = idx & 7;
            *reinterpret_cast<bf16x8*>((char*)Ks + swz(row, row * 128 + ch * 16)) = stK[i];
            *reinterpret_cast<bf16x8*>((char*)Vs + swz(row, row * 128 + ch * 16)) = stV[i];
        }
        if (kt + 1 < 32) {   // issue next-tile loads under this tile's compute
#pragma unroll
            for (int i = 0; i < 2; ++i) {
                int idx = tid + 256 * i;
                int row = idx >> 3, ch = idx & 7;
                stK[i] = *reinterpret_cast<const bf16x8*>(
                    kmat + (tok0 + (kt + 1) * 64 + row) * DM + h * 64 + ch * 8);
                stV[i] = *reinterpret_cast<const bf16x8*>(
                    vT + ((size_t)bh * 64 + row) * SS + (kt + 1) * 64 + ch * 8);
            }
        }
        __syncthreads();   // staged tile visible

        // S^T[key][q] = K . Q^T, C-init = per-key bias (-inf for padded keys)
        f32x16 s0 = *reinterpret_cast<const f32x16*>(bbase + kt * 64);
        f32x16 s1 = *reinterpret_cast<const f32x16*>(bbase + kt * 64 + 32);
#pragma unroll
        for (int ks = 0; ks < 4; ++ks) {
            bf16x8 k0 = *reinterpret_cast<const bf16x8*>(kR0 + (cx ^ (ks * 32)));
            bf16x8 k1 = *reinterpret_cast<const bf16x8*>(kR1 + (cx ^ (ks * 32)));
            s0 = __builtin_amdgcn_mfma_f32_32x32x16_bf16(k0, qf[ks], s0, 0, 0, 0);
            s1 = __builtin_amdgcn_mfma_f32_32x32x16_bf16(k1, qf[ks], s1, 0, 0, 0);
        }

        // online softmax in log2 domain, max3-friendly tree
        float pm = fmaxf(s0[0], s0[1]);
#pragma unroll
        for (int e = 2; e < 16; e += 2) pm = fmaxf(pm, fmaxf(s0[e], s0[e + 1]));
#pragma unroll
        for (int e = 0; e < 16; e += 2) pm = fmaxf(pm, fmaxf(s1[e], s1[e + 1]));
        pm = fmaxf(pm, __shfl_xor(pm, 32));

        if (!__all(pm <= mrow + 11.0f)) {   // T13 defer-max (p bounded by 2^11)
            float mnew = fmaxf(mrow, pm);
            float scf = fexp2(mrow - mnew);
            mrow = mnew;
            lrow *= scf;
#pragma unroll
            for (int e = 0; e < 16; ++e) { oA[e] *= scf; oB[e] *= scf; }
        }

        float p0[16], p1[16], psum = 0.f;
#pragma unroll
        for (int e = 0; e < 16; ++e) {
            p0[e] = fexp2(s0[e] - mrow); psum += p0[e];
            p1[e] = fexp2(s1[e] - mrow); psum += p1[e];
        }
        psum += __shfl_xor(psum, 32);
        lrow += psum;

        // P -> bf16 B-fragments (cvt_pk + permlane32_swap), PV MFMA
#pragma unroll
        for (int kk = 0; kk < 4; ++kk) {
            const float* pp = (kk < 2) ? p0 : p1;
            const int ks2 = kk & 1;
            uint32_t c0 = cvtpk(pp[8 * ks2 + 0], pp[8 * ks2 + 1]);
            uint32_t c1 = cvtpk(pp[8 * ks2 + 2], pp[8 * ks2 + 3]);
            uint32_t c2 = cvtpk(pp[8 * ks2 + 4], pp[8 * ks2 + 5]);
            uint32_t c3 = cvtpk(pp[8 * ks2 + 6], pp[8 * ks2 + 7]);
            asm("v_permlane32_swap_b32 %0, %1" : "+v"(c0), "+v"(c2));
            asm("v_permlane32_swap_b32 %0, %1" : "+v"(c1), "+v"(c3));
            union { uint32_t u[4]; bf16x8 v; } pu;
            pu.u[0] = c0; pu.u[1] = c1; pu.u[2] = c2; pu.u[3] = c3;
            bf16x8 vf0 = *reinterpret_cast<const bf16x8*>(vR0 + (cx ^ (kk * 32)));
            bf16x8 vf1 = *reinterpret_cast<const bf16x8*>(vR1 + (cx ^ (kk * 32)));
            oA = __builtin_amdgcn_mfma_f32_32x32x16_bf16(vf0, pu.v, oA, 0, 0, 0);
            oB = __builtin_amdgcn_mfma_f32_32x32x16_bf16(vf1, pu.v, oB, 0, 0, 0);
        }
    }

    // epilogue: O^T rows d = {0,32} + 4*hi + 8*g + r, col q = lane&31
    float inv = 1.0f / lrow;
#pragma unroll
    for (int g = 0; g < 4; ++g) {
        bf16x4 w0, w1;
#pragma unroll
        for (int r = 0; r < 4; ++r) {
            w0[r] = (bf16)(oA[g * 4 + r] * inv);
            w1[r] = (bf16)(oB[g * 4 + r] * inv);
        }
        int d0 = 4 * hi + 8 * g;
        bf16* cp = concat + (tok0 + qrow0 + lq) * DM + h * 64 + d0;
        *reinterpret_cast<bf16x4*>(cp) = w0;
        *reinterpret_cast<bf16x4*>(cp + 32) = w1;
    }
}

extern "C" void kernel_launch(void* const* d_in, const int* in_sizes, int n_in,
                              void* d_out, int out_size, void* d_ws, size_t ws_size,
                              hipStream_t stream)
{
    const float* x  = (const float*)d_in[0];
    const int* mask = (const int*)d_in[1];
    const float* Wq = (const float*)d_in[2];
    const float* Wk = (const float*)d_in[3];
    const float* Wv = (const float*)d_in[4];
    const float* Wo = (const float*)d_in[5];
    float* out = (float*)d_out;

    // workspace (72 MiB), time-multiplexed:
    //  [0,16)  xb -> vT   [16,18) wq -> bias   [18,20) wk  [20,22) wv  [22,24) wob
    //  [24,40) qbuf  [40,56) kbuf  [56,72) vbuf -> concat
    char* ws = (char*)d_ws;
    bf16* xb    = (bf16*)(ws);
    bf16* wq    = (bf16*)(ws + (16ull << 20));
    bf16* wk    = (bf16*)(ws + (18ull << 20));
    bf16* wv    = (bf16*)(ws + (20ull << 20));
    bf16* wob   = (bf16*)(ws + (22ull << 20));
    bf16* qbuf  = (bf16*)(ws + (24ull << 20));
    bf16* kbuf  = (bf16*)(ws + (40ull << 20));
    bf16* vbuf  = (bf16*)(ws + (56ull << 20));
    bf16* vT    = xb;                       // xb dead after QKV gemms
    bf16* concat = vbuf;                    // vbuf dead after vtrans
    float* bias = (float*)wq;               // wq dead after QKV gemms

    cvt_kernel<<<dim3((NTOK * DM / 8) / 256), 256, 0, stream>>>(x, xb, NTOK * DM / 8);
    cvt_kernel<<<dim3((DM * DM / 8) / 256), 256, 0, stream>>>(Wq, wq, DM * DM / 8);
    cvt_kernel<<<dim3((DM * DM / 8) / 256), 256, 0, stream>>>(Wk, wk, DM * DM / 8);
    cvt_kernel<<<dim3((DM * DM / 8) / 256), 256, 0, stream>>>(Wv, wv, DM * DM / 8);
    cvt_kernel<<<dim3((DM * DM / 8) / 256), 256, 0, stream>>>(Wo, wob, DM * DM / 8);

    gemm_bt<bf16><<<dim3(DM / 128, NTOK / 128), 256, 0, stream>>>(xb, wq, qbuf, NTOK, DM, DM);
    gemm_bt<bf16><<<dim3(DM / 128, NTOK / 128), 256, 0, stream>>>(xb, wk, kbuf, NTOK, DM, DM);
    gemm_bt<bf16><<<dim3(DM / 128, NTOK / 128), 256, 0, stream>>>(xb, wv, vbuf, NTOK, DM, DM);

    vtrans_kernel<<<dim3(SS / 64, BB * NH), 256, 0, stream>>>(vbuf, vT);
    biasprep_kernel<<<dim3(40), 256, 0, stream>>>(mask, bias);

    attn_kernel<<<dim3(SS / 128, BB * NH), 256, 0, stream>>>(qbuf, kbuf, vT, mask, bias, concat);

    gemm_bt<float><<<dim3(DM / 128, NTOK / 128), 256, 0, stream>>>(concat, wob, out, NTOK, DM, DM);
}

// Round 5
// 234.453 us; speedup vs baseline: 1.7072x; 1.1211x over previous
//
#include <hip/hip_runtime.h>
#include <stdint.h>

// MultiHeadAttention: B=4, S=2048, D_MODEL=1024, H=16, d_k=d_v=64
// Round 5: identical to round 4 except the attn grid-size bug is fixed
// (128 -> 1024 blocks). dbuf LDS + one barrier/tile attn, setprio, XCD
// swizzles, fused QKV GEMM (N=3072), concat in dead V-columns of qkv.

typedef __bf16 bf16;
typedef __bf16 bf16x8 __attribute__((ext_vector_type(8)));
typedef __bf16 bf16x4 __attribute__((ext_vector_type(4)));
typedef float f32x4 __attribute__((ext_vector_type(4)));
typedef float f32x16 __attribute__((ext_vector_type(16)));

#define DM    1024
#define NH    16
#define SS    2048
#define BB    4
#define NTOK  8192
#define QKVLD 3072
#define LOG2E_DIV8 0.18033688011112042f   // log2(e)/8: scale folded into Q, exp2 domain

__device__ __forceinline__ int swz(int row, int byteoff) {
    return byteoff ^ ((row & 7) << 4);
}
__device__ __forceinline__ float fexp2(float x) {
    float r; asm("v_exp_f32 %0, %1" : "=v"(r) : "v"(x)); return r;
}
__device__ __forceinline__ uint32_t cvtpk(float lo, float hi_) {
    uint32_t r; asm("v_cvt_pk_bf16_f32 %0, %1, %2" : "=v"(r) : "v"(lo), "v"(hi_)); return r;
}
__device__ __forceinline__ void gload_lds16(const void* g, void* l) {
    __builtin_amdgcn_global_load_lds(
        (const __attribute__((address_space(1))) uint32_t*)g,
        (__attribute__((address_space(3))) uint32_t*)l, 16, 0, 0);
}

__global__ void cvt_kernel(const float* __restrict__ in, bf16* __restrict__ out, int n8) {
    int i = blockIdx.x * blockDim.x + threadIdx.x;
    if (i >= n8) return;
    const float4* p = reinterpret_cast<const float4*>(in) + (size_t)i * 2;
    float4 a = p[0], b = p[1];
    bf16x8 o;
    o[0] = (bf16)a.x; o[1] = (bf16)a.y; o[2] = (bf16)a.z; o[3] = (bf16)a.w;
    o[4] = (bf16)b.x; o[5] = (bf16)b.y; o[6] = (bf16)b.z; o[7] = (bf16)b.w;
    reinterpret_cast<bf16x8*>(out)[i] = o;
}

// all 4 weight matrices (1M fp32 each) in one launch
__global__ void wcvt_kernel(const float* __restrict__ wq, const float* __restrict__ wk,
                            const float* __restrict__ wv, const float* __restrict__ wo,
                            bf16* __restrict__ wqkv, bf16* __restrict__ wob) {
    int i = blockIdx.x * blockDim.x + threadIdx.x;   // 8-elem group id, 4*131072 total
    int seg = i >> 17, off = i & 131071;
    const float* src = (seg == 0) ? wq : (seg == 1) ? wk : (seg == 2) ? wv : wo;
    bf16* dst = (seg < 3) ? (wqkv + (size_t)seg * DM * DM) : wob;
    const float4* p = reinterpret_cast<const float4*>(src) + (size_t)off * 2;
    float4 a = p[0], b = p[1];
    bf16x8 o;
    o[0] = (bf16)a.x; o[1] = (bf16)a.y; o[2] = (bf16)a.z; o[3] = (bf16)a.w;
    o[4] = (bf16)b.x; o[5] = (bf16)b.y; o[6] = (bf16)b.z; o[7] = (bf16)b.w;
    reinterpret_cast<bf16x8*>(dst)[off] = o;
}

// bias[b5][kt][hs][hi][e]: -inf where key padded; slice b=4 all zero (padded-q lanes).
__global__ void biasprep_kernel(const int* __restrict__ mask, float* __restrict__ bias) {
    int idx = blockIdx.x * blockDim.x + threadIdx.x;
    if (idx >= 5 * 2048) return;
    int e = idx & 15, hi = (idx >> 4) & 1, hs = (idx >> 5) & 1;
    int kt = (idx >> 6) & 31, b = idx >> 11;
    int key = 32 * hs + 4 * hi + 8 * (e >> 2) + (e & 3);
    float v = 0.f;
    if (b < 4 && mask[b * SS + kt * 64 + key]) v = -__builtin_inff();
    bias[idx] = v;
}

// C[M,N] = A[M,K](lda) * Bm[N,K]^T. 128x128 tile, BK=64, 4 waves, 16x16x32 MFMA.
// global_load_lds w=16 staging; XCD-chunked block swizzle (nwg % 8 == 0).
template <typename OT>
__global__ __launch_bounds__(256) void gemm_bt(
    const bf16* __restrict__ A, int lda, const bf16* __restrict__ Bm, OT* __restrict__ C,
    int M, int N, int K)
{
    __shared__ bf16 As[128 * 64];
    __shared__ bf16 Bs[128 * 64];

    const int nwg = gridDim.x * gridDim.y;
    const int wg = blockIdx.y * gridDim.x + blockIdx.x;
    const int nsw = (wg & 7) * (nwg >> 3) + (wg >> 3);
    const int tn = nsw % gridDim.x, tm = nsw / gridDim.x;

    const int tid = threadIdx.x;
    const int lane = tid & 63, wv = tid >> 6;
    const int wr = wv >> 1, wc = wv & 1;
    const int lr = lane & 15, lg = lane >> 4;

    const f32x4 zero = {0.f, 0.f, 0.f, 0.f};
    f32x4 acc[4][4];
#pragma unroll
    for (int mi = 0; mi < 4; ++mi)
#pragma unroll
        for (int ni = 0; ni < 4; ++ni) acc[mi][ni] = zero;

    const char* Abase = (const char*)(A + (size_t)(tm * 128) * lda);
    const char* Bbase = (const char*)(Bm + (size_t)(tn * 128) * K);

    for (int k0 = 0; k0 < K; k0 += 64) {
#pragma unroll
        for (int i = 0; i < 4; ++i) {
            int idx = tid + 256 * i;
            int row = idx >> 3, ch = idx & 7;
            int gcol = (ch * 16) ^ ((row & 7) << 4);   // pre-swizzled source column
            gload_lds16(Abase + (size_t)row * (lda * 2) + k0 * 2 + gcol, (char*)As + idx * 16);
            gload_lds16(Bbase + (size_t)row * (K * 2) + k0 * 2 + gcol, (char*)Bs + idx * 16);
        }
        __syncthreads();

#pragma unroll
        for (int ks = 0; ks < 2; ++ks) {
            bf16x8 af[4], bfr[4];
#pragma unroll
            for (int mi = 0; mi < 4; ++mi) {
                int row = wr * 64 + mi * 16 + lr;
                af[mi] = *reinterpret_cast<const bf16x8*>(
                    (char*)As + swz(row, row * 128 + ks * 64 + lg * 16));
            }
#pragma unroll
            for (int ni = 0; ni < 4; ++ni) {
                int row = wc * 64 + ni * 16 + lr;
                bfr[ni] = *reinterpret_cast<const bf16x8*>(
                    (char*)Bs + swz(row, row * 128 + ks * 64 + lg * 16));
            }
#pragma unroll
            for (int mi = 0; mi < 4; ++mi)
#pragma unroll
                for (int ni = 0; ni < 4; ++ni)
                    acc[mi][ni] = __builtin_amdgcn_mfma_f32_16x16x32_bf16(
                        af[mi], bfr[ni], acc[mi][ni], 0, 0, 0);
        }
        __syncthreads();
    }

#pragma unroll
    for (int mi = 0; mi < 4; ++mi)
#pragma unroll
        for (int ni = 0; ni < 4; ++ni)
#pragma unroll
            for (int r = 0; r < 4; ++r) {
                int row = tm * 128 + wr * 64 + mi * 16 + lg * 4 + r;
                int col = tn * 128 + wc * 64 + ni * 16 + lr;
                C[(size_t)row * N + col] = (OT)acc[mi][ni][r];
            }
}

// Transpose V: vb[token][ldv] head-cols -> vT[(bh*64+d)][s]
__global__ __launch_bounds__(256) void vtrans_kernel(
    const bf16* __restrict__ vb, int ldv, bf16* __restrict__ vT)
{
    const int st = blockIdx.x, bh = blockIdx.y;
    const int b = bh >> 4, h = bh & 15;
    const int tid = threadIdx.x;
    __shared__ bf16 T[64 * 64];
#pragma unroll
    for (int i = 0; i < 2; ++i) {
        int idx = tid + 256 * i;
        int s = idx >> 3, ch = idx & 7;
        bf16x8 v = *reinterpret_cast<const bf16x8*>(
            vb + (size_t)(b * SS + st * 64 + s) * ldv + h * 64 + ch * 8);
        *reinterpret_cast<bf16x8*>((char*)T + swz(s, s * 128 + ch * 16)) = v;
    }
    __syncthreads();
#pragma unroll
    for (int i = 0; i < 2; ++i) {
        int idx = tid + 256 * i;
        int d = idx >> 3, ch = idx & 7;
        bf16x8 o;
#pragma unroll
        for (int j = 0; j < 8; ++j) {
            int s = ch * 8 + j;
            o[j] = *reinterpret_cast<const bf16*>((char*)T + swz(s, s * 128 + d * 2));
        }
        *reinterpret_cast<bf16x8*>(vT + ((size_t)bh * 64 + d) * SS + st * 64 + ch * 8) = o;
    }
}

// Flash attention: dbuf LDS, one barrier/tile, loads issued at region start.
__global__ __launch_bounds__(256) void attn_kernel(
    const bf16* __restrict__ qkv, const bf16* __restrict__ vT,
    const float* __restrict__ bias, const int* __restrict__ mask,
    bf16* __restrict__ concat)
{
    // XCD-chunked swizzle: each XCD gets 8 bh's (16 qt-blocks each share 512KB K/V in L2)
    const int w = blockIdx.x;                 // 0..1023
    const int nw = (w & 7) * 128 + (w >> 3);
    const int qt = nw & 15, bh = nw >> 4;
    const int b = bh >> 4, h = bh & 15;
    const int tid = threadIdx.x;
    const int lane = tid & 63, wv = tid >> 6;
    const int lq = lane & 31, hi = lane >> 5;

    __shared__ bf16 Ks[2][64 * 64];   // [key][d] swizzled
    __shared__ bf16 Vs[2][64 * 64];   // [d][key] swizzled

    const size_t tok0 = (size_t)b * SS;
    const int qrow0 = qt * 128 + wv * 32;

    const int qpad = mask[tok0 + qrow0 + lq];
    bf16x8 qf[4];
    {
        const bf16* qp = qkv + (tok0 + qrow0 + lq) * QKVLD + h * 64 + hi * 8;
#pragma unroll
        for (int ks = 0; ks < 4; ++ks) {
            bf16x8 v = *reinterpret_cast<const bf16x8*>(qp + ks * 16);
#pragma unroll
            for (int j = 0; j < 8; ++j)
                v[j] = qpad ? (bf16)0.f : (bf16)((float)v[j] * LOG2E_DIV8);
            qf[ks] = v;
        }
    }
    const float* bbase = bias + (size_t)(qpad ? 4 : b) * 2048 + hi * 16;

    float mrow = -3e38f, lrow = 0.f;
    f32x16 oA, oB;
#pragma unroll
    for (int e = 0; e < 16; ++e) { oA[e] = 0.f; oB[e] = 0.f; }

    // staging addresses (per thread, 2 chunks)
    const int srow[2] = { tid >> 3, (tid + 256) >> 3 };
    const int sch[2]  = { tid & 7, tid & 7 };
    const bf16* kbase = qkv + 1024 + h * 64;
    const int cx = (hi * 16) ^ ((lq & 7) << 4);

    // prologue: stage tile 0
    bf16x8 stK[2], stV[2];
#pragma unroll
    for (int i = 0; i < 2; ++i) {
        stK[i] = *reinterpret_cast<const bf16x8*>(
            kbase + (tok0 + srow[i]) * QKVLD + sch[i] * 8);
        stV[i] = *reinterpret_cast<const bf16x8*>(
            vT + ((size_t)bh * 64 + srow[i]) * SS + sch[i] * 8);
    }
#pragma unroll
    for (int i = 0; i < 2; ++i) {
        *reinterpret_cast<bf16x8*>((char*)Ks[0] + swz(srow[i], srow[i] * 128 + sch[i] * 16)) = stK[i];
        *reinterpret_cast<bf16x8*>((char*)Vs[0] + swz(srow[i], srow[i] * 128 + sch[i] * 16)) = stV[i];
    }
    __syncthreads();

    for (int kt = 0; kt < 32; ++kt) {
        const int cur = kt & 1;
        // (1) issue next tile's global loads — vmcnt wait lands at (5), a full tile later
        if (kt < 31) {
#pragma unroll
            for (int i = 0; i < 2; ++i) {
                stK[i] = *reinterpret_cast<const bf16x8*>(
                    kbase + (tok0 + (kt + 1) * 64 + srow[i]) * QKVLD + sch[i] * 8);
                stV[i] = *reinterpret_cast<const bf16x8*>(
                    vT + ((size_t)bh * 64 + srow[i]) * SS + (kt + 1) * 64 + sch[i] * 8);
            }
        }
        const char* kB = (const char*)Ks[cur];
        const char* vB = (const char*)Vs[cur];
        const int off0 = lq * 128 + cx, off1 = (32 + lq) * 128 + cx;

        // (2) QK^T with bias C-init
        f32x16 s0 = *reinterpret_cast<const f32x16*>(bbase + kt * 64);
        f32x16 s1 = *reinterpret_cast<const f32x16*>(bbase + kt * 64 + 32);
        __builtin_amdgcn_s_setprio(1);
#pragma unroll
        for (int ks = 0; ks < 4; ++ks) {
            bf16x8 k0 = *reinterpret_cast<const bf16x8*>(kB + (off0 ^ (ks * 32)));
            bf16x8 k1 = *reinterpret_cast<const bf16x8*>(kB + (off1 ^ (ks * 32)));
            s0 = __builtin_amdgcn_mfma_f32_32x32x16_bf16(k0, qf[ks], s0, 0, 0, 0);
            s1 = __builtin_amdgcn_mfma_f32_32x32x16_bf16(k1, qf[ks], s1, 0, 0, 0);
        }
        __builtin_amdgcn_s_setprio(0);

        // (3) online softmax (log2 domain)
        float pm = fmaxf(s0[0], s0[1]);
#pragma unroll
        for (int e = 2; e < 16; e += 2) pm = fmaxf(pm, fmaxf(s0[e], s0[e + 1]));
#pragma unroll
        for (int e = 0; e < 16; e += 2) pm = fmaxf(pm, fmaxf(s1[e], s1[e + 1]));
        pm = fmaxf(pm, __shfl_xor(pm, 32));

        if (!__all(pm <= mrow + 11.0f)) {   // T13 defer-max
            float mnew = fmaxf(mrow, pm);
            float scf = fexp2(mrow - mnew);
            mrow = mnew;
            lrow *= scf;
#pragma unroll
            for (int e = 0; e < 16; ++e) { oA[e] *= scf; oB[e] *= scf; }
        }

        float p0[16], p1[16];
        float ps0 = 0.f, ps1 = 0.f, ps2 = 0.f, ps3 = 0.f;
#pragma unroll
        for (int e = 0; e < 16; e += 2) {
            p0[e] = fexp2(s0[e] - mrow);     ps0 += p0[e];
            p0[e + 1] = fexp2(s0[e + 1] - mrow); ps1 += p0[e + 1];
            p1[e] = fexp2(s1[e] - mrow);     ps2 += p1[e];
            p1[e + 1] = fexp2(s1[e + 1] - mrow); ps3 += p1[e + 1];
        }
        float psum = (ps0 + ps1) + (ps2 + ps3);
        psum += __shfl_xor(psum, 32);
        lrow += psum;

        // (4) PV: pack P -> bf16 fragments, MFMA
        __builtin_amdgcn_s_setprio(1);
#pragma unroll
        for (int kk = 0; kk < 4; ++kk) {
            const float* pp = (kk < 2) ? p0 : p1;
            const int ks2 = kk & 1;
            uint32_t c0 = cvtpk(pp[8 * ks2 + 0], pp[8 * ks2 + 1]);
            uint32_t c1 = cvtpk(pp[8 * ks2 + 2], pp[8 * ks2 + 3]);
            uint32_t c2 = cvtpk(pp[8 * ks2 + 4], pp[8 * ks2 + 5]);
            uint32_t c3 = cvtpk(pp[8 * ks2 + 6], pp[8 * ks2 + 7]);
            asm("v_permlane32_swap_b32 %0, %1" : "+v"(c0), "+v"(c2));
            asm("v_permlane32_swap_b32 %0, %1" : "+v"(c1), "+v"(c3));
            union { uint32_t u[4]; bf16x8 v; } pu;
            pu.u[0] = c0; pu.u[1] = c1; pu.u[2] = c2; pu.u[3] = c3;
            bf16x8 vf0 = *reinterpret_cast<const bf16x8*>(vB + (off0 ^ (kk * 32)));
            bf16x8 vf1 = *reinterpret_cast<const bf16x8*>(vB + (off1 ^ (kk * 32)));
            oA = __builtin_amdgcn_mfma_f32_32x32x16_bf16(vf0, pu.v, oA, 0, 0, 0);
            oB = __builtin_amdgcn_mfma_f32_32x32x16_bf16(vf1, pu.v, oB, 0, 0, 0);
        }
        __builtin_amdgcn_s_setprio(0);

        // (5) write next tile into the other buffer (waits on (1)'s loads — slack ≈ full tile)
        if (kt < 31) {
#pragma unroll
            for (int i = 0; i < 2; ++i) {
                *reinterpret_cast<bf16x8*>(
                    (char*)Ks[cur ^ 1] + swz(srow[i], srow[i] * 128 + sch[i] * 16)) = stK[i];
                *reinterpret_cast<bf16x8*>(
                    (char*)Vs[cur ^ 1] + swz(srow[i], srow[i] * 128 + sch[i] * 16)) = stV[i];
            }
            __syncthreads();
        }
    }

    // epilogue: O^T rows d = {0,32} + 4*hi + 8*g + r, col q = lane&31
    float inv = 1.0f / lrow;
#pragma unroll
    for (int g = 0; g < 4; ++g) {
        bf16x4 w0, w1;
#pragma unroll
        for (int r = 0; r < 4; ++r) {
            w0[r] = (bf16)(oA[g * 4 + r] * inv);
            w1[r] = (bf16)(oB[g * 4 + r] * inv);
        }
        int d0 = 4 * hi + 8 * g;
        bf16* cp = concat + (tok0 + qrow0 + lq) * QKVLD + h * 64 + d0;
        *reinterpret_cast<bf16x4*>(cp) = w0;
        *reinterpret_cast<bf16x4*>(cp + 32) = w1;
    }
}

extern "C" void kernel_launch(void* const* d_in, const int* in_sizes, int n_in,
                              void* d_out, int out_size, void* d_ws, size_t ws_size,
                              hipStream_t stream)
{
    const float* x  = (const float*)d_in[0];
    const int* mask = (const int*)d_in[1];
    const float* Wq = (const float*)d_in[2];
    const float* Wk = (const float*)d_in[3];
    const float* Wv = (const float*)d_in[4];
    const float* Wo = (const float*)d_in[5];
    float* out = (float*)d_out;

    // workspace (72 MiB):
    //  [0,16)  xb -> vT (xb dead after QKV gemm)
    //  [16,22) wqkv -> bias (dead after QKV gemm)   [22,24) wob
    //  [24,72) qkv [8192][3072]; v-cols (2048..3071) become concat after vtrans
    char* ws = (char*)d_ws;
    bf16* xb    = (bf16*)(ws);
    bf16* wqkv  = (bf16*)(ws + (16ull << 20));
    bf16* wob   = (bf16*)(ws + (22ull << 20));
    bf16* qkv   = (bf16*)(ws + (24ull << 20));
    bf16* vT    = xb;
    float* bias = (float*)wqkv;
    bf16* concat = qkv + 2048;   // strided [8192][.] within qkv, stride 3072

    cvt_kernel<<<dim3((NTOK * DM / 8) / 256), 256, 0, stream>>>(x, xb, NTOK * DM / 8);
    wcvt_kernel<<<dim3(2048), 256, 0, stream>>>(Wq, Wk, Wv, Wo, wqkv, wob);

    // fused QKV projection: qkv[8192,3072] = xb[8192,1024] @ wqkv[3072,1024]^T
    gemm_bt<bf16><<<dim3(QKVLD / 128, NTOK / 128), 256, 0, stream>>>(
        xb, DM, wqkv, qkv, NTOK, QKVLD, DM);

    vtrans_kernel<<<dim3(SS / 64, BB * NH), 256, 0, stream>>>(qkv + 2048, QKVLD, vT);
    biasprep_kernel<<<dim3(40), 256, 0, stream>>>(mask, bias);

    // (SS/128) q-tiles * BB*NH heads = 16 * 64 = 1024 blocks  [round-4 bug: was 128]
    attn_kernel<<<dim3((SS / 128) * (BB * NH)), 256, 0, stream>>>(
        qkv, vT, bias, mask, concat);

    // output projection: out = concat(lda=3072) @ wob^T
    gemm_bt<float><<<dim3(DM / 128, NTOK / 128), 256, 0, stream>>>(
        concat, QKVLD, wob, out, NTOK, DM, DM);
}

// Round 6
// 226.561 us; speedup vs baseline: 1.7667x; 1.0348x over previous
//
#include <hip/hip_runtime.h>
#include <stdint.h>

// MultiHeadAttention: B=4, S=2048, D_MODEL=1024, H=16, d_k=d_v=64
// Round 6: attn K/V staging moved to global_load_lds (no VGPR dest -> the
// register allocator cannot sink the prefetch; true async DMA with a full
// tile of slack before the barrier drain). Source-side pre-swizzle, linear
// LDS dest (T21 both-sides). Bias loads issued before DMA so their vmcnt
// wait leaves the DMA in flight. Rest identical to round 5.

typedef __bf16 bf16;
typedef __bf16 bf16x8 __attribute__((ext_vector_type(8)));
typedef __bf16 bf16x4 __attribute__((ext_vector_type(4)));
typedef float f32x4 __attribute__((ext_vector_type(4)));
typedef float f32x16 __attribute__((ext_vector_type(16)));

#define DM    1024
#define NH    16
#define SS    2048
#define BB    4
#define NTOK  8192
#define QKVLD 3072
#define LOG2E_DIV8 0.18033688011112042f   // log2(e)/8: scale folded into Q, exp2 domain

__device__ __forceinline__ int swz(int row, int byteoff) {
    return byteoff ^ ((row & 7) << 4);
}
__device__ __forceinline__ float fexp2(float x) {
    float r; asm("v_exp_f32 %0, %1" : "=v"(r) : "v"(x)); return r;
}
__device__ __forceinline__ uint32_t cvtpk(float lo, float hi_) {
    uint32_t r; asm("v_cvt_pk_bf16_f32 %0, %1, %2" : "=v"(r) : "v"(lo), "v"(hi_)); return r;
}
__device__ __forceinline__ void gload_lds16(const void* g, void* l) {
    __builtin_amdgcn_global_load_lds(
        (const __attribute__((address_space(1))) uint32_t*)g,
        (__attribute__((address_space(3))) uint32_t*)l, 16, 0, 0);
}

__global__ void cvt_kernel(const float* __restrict__ in, bf16* __restrict__ out, int n8) {
    int i = blockIdx.x * blockDim.x + threadIdx.x;
    if (i >= n8) return;
    const float4* p = reinterpret_cast<const float4*>(in) + (size_t)i * 2;
    float4 a = p[0], b = p[1];
    bf16x8 o;
    o[0] = (bf16)a.x; o[1] = (bf16)a.y; o[2] = (bf16)a.z; o[3] = (bf16)a.w;
    o[4] = (bf16)b.x; o[5] = (bf16)b.y; o[6] = (bf16)b.z; o[7] = (bf16)b.w;
    reinterpret_cast<bf16x8*>(out)[i] = o;
}

// all 4 weight matrices (1M fp32 each) in one launch
__global__ void wcvt_kernel(const float* __restrict__ wq, const float* __restrict__ wk,
                            const float* __restrict__ wv, const float* __restrict__ wo,
                            bf16* __restrict__ wqkv, bf16* __restrict__ wob) {
    int i = blockIdx.x * blockDim.x + threadIdx.x;   // 8-elem group id, 4*131072 total
    int seg = i >> 17, off = i & 131071;
    const float* src = (seg == 0) ? wq : (seg == 1) ? wk : (seg == 2) ? wv : wo;
    bf16* dst = (seg < 3) ? (wqkv + (size_t)seg * DM * DM) : wob;
    const float4* p = reinterpret_cast<const float4*>(src) + (size_t)off * 2;
    float4 a = p[0], b = p[1];
    bf16x8 o;
    o[0] = (bf16)a.x; o[1] = (bf16)a.y; o[2] = (bf16)a.z; o[3] = (bf16)a.w;
    o[4] = (bf16)b.x; o[5] = (bf16)b.y; o[6] = (bf16)b.z; o[7] = (bf16)b.w;
    reinterpret_cast<bf16x8*>(dst)[off] = o;
}

// bias[b5][kt][hs][hi][e]: -inf where key padded; slice b=4 all zero (padded-q lanes).
__global__ void biasprep_kernel(const int* __restrict__ mask, float* __restrict__ bias) {
    int idx = blockIdx.x * blockDim.x + threadIdx.x;
    if (idx >= 5 * 2048) return;
    int e = idx & 15, hi = (idx >> 4) & 1, hs = (idx >> 5) & 1;
    int kt = (idx >> 6) & 31, b = idx >> 11;
    int key = 32 * hs + 4 * hi + 8 * (e >> 2) + (e & 3);
    float v = 0.f;
    if (b < 4 && mask[b * SS + kt * 64 + key]) v = -__builtin_inff();
    bias[idx] = v;
}

// C[M,N] = A[M,K](lda) * Bm[N,K]^T. 128x128 tile, BK=64, 4 waves, 16x16x32 MFMA.
template <typename OT>
__global__ __launch_bounds__(256) void gemm_bt(
    const bf16* __restrict__ A, int lda, const bf16* __restrict__ Bm, OT* __restrict__ C,
    int M, int N, int K)
{
    __shared__ bf16 As[128 * 64];
    __shared__ bf16 Bs[128 * 64];

    const int nwg = gridDim.x * gridDim.y;
    const int wg = blockIdx.y * gridDim.x + blockIdx.x;
    const int nsw = (wg & 7) * (nwg >> 3) + (wg >> 3);
    const int tn = nsw % gridDim.x, tm = nsw / gridDim.x;

    const int tid = threadIdx.x;
    const int lane = tid & 63, wv = tid >> 6;
    const int wr = wv >> 1, wc = wv & 1;
    const int lr = lane & 15, lg = lane >> 4;

    const f32x4 zero = {0.f, 0.f, 0.f, 0.f};
    f32x4 acc[4][4];
#pragma unroll
    for (int mi = 0; mi < 4; ++mi)
#pragma unroll
        for (int ni = 0; ni < 4; ++ni) acc[mi][ni] = zero;

    const char* Abase = (const char*)(A + (size_t)(tm * 128) * lda);
    const char* Bbase = (const char*)(Bm + (size_t)(tn * 128) * K);

    for (int k0 = 0; k0 < K; k0 += 64) {
#pragma unroll
        for (int i = 0; i < 4; ++i) {
            int idx = tid + 256 * i;
            int row = idx >> 3, ch = idx & 7;
            int gcol = (ch * 16) ^ ((row & 7) << 4);   // pre-swizzled source column
            gload_lds16(Abase + (size_t)row * (lda * 2) + k0 * 2 + gcol, (char*)As + idx * 16);
            gload_lds16(Bbase + (size_t)row * (K * 2) + k0 * 2 + gcol, (char*)Bs + idx * 16);
        }
        __syncthreads();

#pragma unroll
        for (int ks = 0; ks < 2; ++ks) {
            bf16x8 af[4], bfr[4];
#pragma unroll
            for (int mi = 0; mi < 4; ++mi) {
                int row = wr * 64 + mi * 16 + lr;
                af[mi] = *reinterpret_cast<const bf16x8*>(
                    (char*)As + swz(row, row * 128 + ks * 64 + lg * 16));
            }
#pragma unroll
            for (int ni = 0; ni < 4; ++ni) {
                int row = wc * 64 + ni * 16 + lr;
                bfr[ni] = *reinterpret_cast<const bf16x8*>(
                    (char*)Bs + swz(row, row * 128 + ks * 64 + lg * 16));
            }
#pragma unroll
            for (int mi = 0; mi < 4; ++mi)
#pragma unroll
                for (int ni = 0; ni < 4; ++ni)
                    acc[mi][ni] = __builtin_amdgcn_mfma_f32_16x16x32_bf16(
                        af[mi], bfr[ni], acc[mi][ni], 0, 0, 0);
        }
        __syncthreads();
    }

#pragma unroll
    for (int mi = 0; mi < 4; ++mi)
#pragma unroll
        for (int ni = 0; ni < 4; ++ni)
#pragma unroll
            for (int r = 0; r < 4; ++r) {
                int row = tm * 128 + wr * 64 + mi * 16 + lg * 4 + r;
                int col = tn * 128 + wc * 64 + ni * 16 + lr;
                C[(size_t)row * N + col] = (OT)acc[mi][ni][r];
            }
}

// Transpose V: vb[token][ldv] head-cols -> vT[(bh*64+d)][s]
__global__ __launch_bounds__(256) void vtrans_kernel(
    const bf16* __restrict__ vb, int ldv, bf16* __restrict__ vT)
{
    const int st = blockIdx.x, bh = blockIdx.y;
    const int b = bh >> 4, h = bh & 15;
    const int tid = threadIdx.x;
    __shared__ bf16 T[64 * 64];
#pragma unroll
    for (int i = 0; i < 2; ++i) {
        int idx = tid + 256 * i;
        int s = idx >> 3, ch = idx & 7;
        bf16x8 v = *reinterpret_cast<const bf16x8*>(
            vb + (size_t)(b * SS + st * 64 + s) * ldv + h * 64 + ch * 8);
        *reinterpret_cast<bf16x8*>((char*)T + swz(s, s * 128 + ch * 16)) = v;
    }
    __syncthreads();
#pragma unroll
    for (int i = 0; i < 2; ++i) {
        int idx = tid + 256 * i;
        int d = idx >> 3, ch = idx & 7;
        bf16x8 o;
#pragma unroll
        for (int j = 0; j < 8; ++j) {
            int s = ch * 8 + j;
            o[j] = *reinterpret_cast<const bf16*>((char*)T + swz(s, s * 128 + d * 2));
        }
        *reinterpret_cast<bf16x8*>(vT + ((size_t)bh * 64 + d) * SS + st * 64 + ch * 8) = o;
    }
}

// Flash attention: global_load_lds dbuf staging, one barrier/tile.
__global__ __launch_bounds__(256) void attn_kernel(
    const bf16* __restrict__ qkv, const bf16* __restrict__ vT,
    const float* __restrict__ bias, const int* __restrict__ mask,
    bf16* __restrict__ concat)
{
    // XCD-chunked swizzle: each XCD gets 8 bh's (16 qt-blocks share K/V in L2)
    const int w = blockIdx.x;                 // 0..1023
    const int nw = (w & 7) * 128 + (w >> 3);
    const int qt = nw & 15, bh = nw >> 4;
    const int b = bh >> 4, h = bh & 15;
    const int tid = threadIdx.x;
    const int lane = tid & 63, wv = tid >> 6;
    const int lq = lane & 31, hi = lane >> 5;

    __shared__ bf16 Ks[2][64 * 64];   // [key][d] swizzled
    __shared__ bf16 Vs[2][64 * 64];   // [d][key] swizzled

    const size_t tok0 = (size_t)b * SS;
    const int qrow0 = qt * 128 + wv * 32;

    const int qpad = mask[tok0 + qrow0 + lq];
    bf16x8 qf[4];
    {
        const bf16* qp = qkv + (tok0 + qrow0 + lq) * QKVLD + h * 64 + hi * 8;
#pragma unroll
        for (int ks = 0; ks < 4; ++ks) {
            bf16x8 v = *reinterpret_cast<const bf16x8*>(qp + ks * 16);
#pragma unroll
            for (int j = 0; j < 8; ++j)
                v[j] = qpad ? (bf16)0.f : (bf16)((float)v[j] * LOG2E_DIV8);
            qf[ks] = v;
        }
    }
    const float* bbase = bias + (size_t)(qpad ? 4 : b) * 2048 + hi * 16;

    float mrow = -3e38f, lrow = 0.f;
    f32x16 oA, oB;
#pragma unroll
    for (int e = 0; e < 16; ++e) { oA[e] = 0.f; oB[e] = 0.f; }

    // DMA staging geometry (per thread, 2 chunks of 16B for K and V each)
    const int srow = tid >> 3, sch = tid & 7;             // chunk 0: rows 0..31
    const int srow2 = (tid + 256) >> 3;                    // chunk 1: rows 32..63
    const int gc1 = (sch * 16) ^ ((srow & 7) << 4);        // pre-swizzled src col
    const int gc2 = (sch * 16) ^ ((srow2 & 7) << 4);
    const char* kSrc = (const char*)(qkv + 1024 + h * 64); // + tokrow*6144 + gcol
    const char* vSrc = (const char*)(vT + (size_t)bh * 64 * SS);
    const size_t kOff1 = (tok0 + srow) * (QKVLD * 2) + gc1;
    const size_t kOff2 = (tok0 + srow2) * (QKVLD * 2) + gc2;
    const size_t vOff1 = (size_t)srow * (SS * 2) + gc1;
    const size_t vOff2 = (size_t)srow2 * (SS * 2) + gc2;
    const int ldsOff1 = tid * 16, ldsOff2 = (tid + 256) * 16;
    const int cx = (hi * 16) ^ ((lq & 7) << 4);

    // prologue: DMA tile 0 into buffer 0
    gload_lds16(kSrc + kOff1, (char*)Ks[0] + ldsOff1);
    gload_lds16(kSrc + kOff2, (char*)Ks[0] + ldsOff2);
    gload_lds16(vSrc + vOff1, (char*)Vs[0] + ldsOff1);
    gload_lds16(vSrc + vOff2, (char*)Vs[0] + ldsOff2);
    __syncthreads();

    for (int kt = 0; kt < 32; ++kt) {
        const int cur = kt & 1;

        // (0) bias loads FIRST (so their vmcnt wait leaves the DMA in flight)
        f32x16 s0 = *reinterpret_cast<const f32x16*>(bbase + kt * 64);
        f32x16 s1 = *reinterpret_cast<const f32x16*>(bbase + kt * 64 + 32);

        // (1) DMA next tile into the other buffer — no VGPR dest, cannot be sunk
        if (kt < 31) {
            const size_t kAdv = (size_t)(kt + 1) * 64 * (QKVLD * 2);
            const size_t vAdv = (size_t)(kt + 1) * 128;
            gload_lds16(kSrc + kOff1 + kAdv, (char*)Ks[cur ^ 1] + ldsOff1);
            gload_lds16(kSrc + kOff2 + kAdv, (char*)Ks[cur ^ 1] + ldsOff2);
            gload_lds16(vSrc + vOff1 + vAdv, (char*)Vs[cur ^ 1] + ldsOff1);
            gload_lds16(vSrc + vOff2 + vAdv, (char*)Vs[cur ^ 1] + ldsOff2);
        }

        const char* kB = (const char*)Ks[cur];
        const char* vB = (const char*)Vs[cur];
        const int off0 = lq * 128 + cx, off1 = (32 + lq) * 128 + cx;

        // (2) QK^T with bias C-init
        __builtin_amdgcn_s_setprio(1);
#pragma unroll
        for (int ks = 0; ks < 4; ++ks) {
            bf16x8 k0 = *reinterpret_cast<const bf16x8*>(kB + (off0 ^ (ks * 32)));
            bf16x8 k1 = *reinterpret_cast<const bf16x8*>(kB + (off1 ^ (ks * 32)));
            s0 = __builtin_amdgcn_mfma_f32_32x32x16_bf16(k0, qf[ks], s0, 0, 0, 0);
            s1 = __builtin_amdgcn_mfma_f32_32x32x16_bf16(k1, qf[ks], s1, 0, 0, 0);
        }
        __builtin_amdgcn_s_setprio(0);

        // (3) online softmax (log2 domain)
        float pm = fmaxf(s0[0], s0[1]);
#pragma unroll
        for (int e = 2; e < 16; e += 2) pm = fmaxf(pm, fmaxf(s0[e], s0[e + 1]));
#pragma unroll
        for (int e = 0; e < 16; e += 2) pm = fmaxf(pm, fmaxf(s1[e], s1[e + 1]));
        pm = fmaxf(pm, __shfl_xor(pm, 32));

        if (!__all(pm <= mrow + 11.0f)) {   // T13 defer-max
            float mnew = fmaxf(mrow, pm);
            float scf = fexp2(mrow - mnew);
            mrow = mnew;
            lrow *= scf;
#pragma unroll
            for (int e = 0; e < 16; ++e) { oA[e] *= scf; oB[e] *= scf; }
        }

        float p0[16], p1[16];
        float ps0 = 0.f, ps1 = 0.f, ps2 = 0.f, ps3 = 0.f;
#pragma unroll
        for (int e = 0; e < 16; e += 2) {
            p0[e] = fexp2(s0[e] - mrow);     ps0 += p0[e];
            p0[e + 1] = fexp2(s0[e + 1] - mrow); ps1 += p0[e + 1];
            p1[e] = fexp2(s1[e] - mrow);     ps2 += p1[e];
            p1[e + 1] = fexp2(s1[e + 1] - mrow); ps3 += p1[e + 1];
        }
        float psum = (ps0 + ps1) + (ps2 + ps3);
        psum += __shfl_xor(psum, 32);
        lrow += psum;

        // (4) PV: pack P -> bf16 fragments, MFMA
        __builtin_amdgcn_s_setprio(1);
#pragma unroll
        for (int kk = 0; kk < 4; ++kk) {
            const float* pp = (kk < 2) ? p0 : p1;
            const int ks2 = kk & 1;
            uint32_t c0 = cvtpk(pp[8 * ks2 + 0], pp[8 * ks2 + 1]);
            uint32_t c1 = cvtpk(pp[8 * ks2 + 2], pp[8 * ks2 + 3]);
            uint32_t c2 = cvtpk(pp[8 * ks2 + 4], pp[8 * ks2 + 5]);
            uint32_t c3 = cvtpk(pp[8 * ks2 + 6], pp[8 * ks2 + 7]);
            asm("v_permlane32_swap_b32 %0, %1" : "+v"(c0), "+v"(c2));
            asm("v_permlane32_swap_b32 %0, %1" : "+v"(c1), "+v"(c3));
            union { uint32_t u[4]; bf16x8 v; } pu;
            pu.u[0] = c0; pu.u[1] = c1; pu.u[2] = c2; pu.u[3] = c3;
            bf16x8 vf0 = *reinterpret_cast<const bf16x8*>(vB + (off0 ^ (kk * 32)));
            bf16x8 vf1 = *reinterpret_cast<const bf16x8*>(vB + (off1 ^ (kk * 32)));
            oA = __builtin_amdgcn_mfma_f32_32x32x16_bf16(vf0, pu.v, oA, 0, 0, 0);
            oB = __builtin_amdgcn_mfma_f32_32x32x16_bf16(vf1, pu.v, oB, 0, 0, 0);
        }
        __builtin_amdgcn_s_setprio(0);

        // (5) end-of-tile barrier: drains the DMA (issued a full tile ago)
        if (kt < 31) __syncthreads();
    }

    // epilogue: O^T rows d = {0,32} + 4*hi + 8*g + r, col q = lane&31
    float inv = 1.0f / lrow;
#pragma unroll
    for (int g = 0; g < 4; ++g) {
        bf16x4 w0, w1;
#pragma unroll
        for (int r = 0; r < 4; ++r) {
            w0[r] = (bf16)(oA[g * 4 + r] * inv);
            w1[r] = (bf16)(oB[g * 4 + r] * inv);
        }
        int d0 = 4 * hi + 8 * g;
        bf16* cp = concat + (tok0 + qrow0 + lq) * QKVLD + h * 64 + d0;
        *reinterpret_cast<bf16x4*>(cp) = w0;
        *reinterpret_cast<bf16x4*>(cp + 32) = w1;
    }
}

extern "C" void kernel_launch(void* const* d_in, const int* in_sizes, int n_in,
                              void* d_out, int out_size, void* d_ws, size_t ws_size,
                              hipStream_t stream)
{
    const float* x  = (const float*)d_in[0];
    const int* mask = (const int*)d_in[1];
    const float* Wq = (const float*)d_in[2];
    const float* Wk = (const float*)d_in[3];
    const float* Wv = (const float*)d_in[4];
    const float* Wo = (const float*)d_in[5];
    float* out = (float*)d_out;

    // workspace (72 MiB):
    //  [0,16)  xb -> vT (xb dead after QKV gemm)
    //  [16,22) wqkv -> bias (dead after QKV gemm)   [22,24) wob
    //  [24,72) qkv [8192][3072]; v-cols (2048..3071) become concat after vtrans
    char* ws = (char*)d_ws;
    bf16* xb    = (bf16*)(ws);
    bf16* wqkv  = (bf16*)(ws + (16ull << 20));
    bf16* wob   = (bf16*)(ws + (22ull << 20));
    bf16* qkv   = (bf16*)(ws + (24ull << 20));
    bf16* vT    = xb;
    float* bias = (float*)wqkv;
    bf16* concat = qkv + 2048;   // strided [8192][.] within qkv, stride 3072

    cvt_kernel<<<dim3((NTOK * DM / 8) / 256), 256, 0, stream>>>(x, xb, NTOK * DM / 8);
    wcvt_kernel<<<dim3(2048), 256, 0, stream>>>(Wq, Wk, Wv, Wo, wqkv, wob);

    // fused QKV projection: qkv[8192,3072] = xb[8192,1024] @ wqkv[3072,1024]^T
    gemm_bt<bf16><<<dim3(QKVLD / 128, NTOK / 128), 256, 0, stream>>>(
        xb, DM, wqkv, qkv, NTOK, QKVLD, DM);

    vtrans_kernel<<<dim3(SS / 64, BB * NH), 256, 0, stream>>>(qkv + 2048, QKVLD, vT);
    biasprep_kernel<<<dim3(40), 256, 0, stream>>>(mask, bias);

    // (SS/128) q-tiles * BB*NH heads = 16 * 64 = 1024 blocks
    attn_kernel<<<dim3((SS / 128) * (BB * NH)), 256, 0, stream>>>(
        qkv, vT, bias, mask, concat);

    // output projection: out = concat(lda=3072) @ wob^T
    gemm_bt<float><<<dim3(DM / 128, NTOK / 128), 256, 0, stream>>>(
        concat, QKVLD, wob, out, NTOK, DM, DM);
}

// Round 7
// 205.951 us; speedup vs baseline: 1.9435x; 1.1001x over previous
//
#include <hip/hip_runtime.h>
#include <stdint.h>

// MultiHeadAttention: B=4, S=2048, D_MODEL=1024, H=16, d_k=d_v=64
// Round 7: attn restructure — 8 waves/block (256 q-rows), KVBLK=128 per iter
// (16 iters), bias slice in LDS (DMA'd once; zero-pad region for padded-q
// lanes), joint softmax over 128 keys. DMA dbuf staging kept from round 6.

typedef __bf16 bf16;
typedef __bf16 bf16x8 __attribute__((ext_vector_type(8)));
typedef __bf16 bf16x4 __attribute__((ext_vector_type(4)));
typedef float f32x4 __attribute__((ext_vector_type(4)));
typedef float f32x16 __attribute__((ext_vector_type(16)));

#define DM    1024
#define NH    16
#define SS    2048
#define BB    4
#define NTOK  8192
#define QKVLD 3072
#define LOG2E_DIV8 0.18033688011112042f   // log2(e)/8: scale folded into Q, exp2 domain

__device__ __forceinline__ int swz(int row, int byteoff) {
    return byteoff ^ ((row & 7) << 4);
}
__device__ __forceinline__ float fexp2(float x) {
    float r; asm("v_exp_f32 %0, %1" : "=v"(r) : "v"(x)); return r;
}
__device__ __forceinline__ uint32_t cvtpk(float lo, float hi_) {
    uint32_t r; asm("v_cvt_pk_bf16_f32 %0, %1, %2" : "=v"(r) : "v"(lo), "v"(hi_)); return r;
}
__device__ __forceinline__ void gload_lds16(const void* g, void* l) {
    __builtin_amdgcn_global_load_lds(
        (const __attribute__((address_space(1))) uint32_t*)g,
        (__attribute__((address_space(3))) uint32_t*)l, 16, 0, 0);
}

__global__ void cvt_kernel(const float* __restrict__ in, bf16* __restrict__ out, int n8) {
    int i = blockIdx.x * blockDim.x + threadIdx.x;
    if (i >= n8) return;
    const float4* p = reinterpret_cast<const float4*>(in) + (size_t)i * 2;
    float4 a = p[0], b = p[1];
    bf16x8 o;
    o[0] = (bf16)a.x; o[1] = (bf16)a.y; o[2] = (bf16)a.z; o[3] = (bf16)a.w;
    o[4] = (bf16)b.x; o[5] = (bf16)b.y; o[6] = (bf16)b.z; o[7] = (bf16)b.w;
    reinterpret_cast<bf16x8*>(out)[i] = o;
}

// all 4 weight matrices (1M fp32 each) in one launch
__global__ void wcvt_kernel(const float* __restrict__ wq, const float* __restrict__ wk,
                            const float* __restrict__ wv, const float* __restrict__ wo,
                            bf16* __restrict__ wqkv, bf16* __restrict__ wob) {
    int i = blockIdx.x * blockDim.x + threadIdx.x;   // 8-elem group id, 4*131072 total
    int seg = i >> 17, off = i & 131071;
    const float* src = (seg == 0) ? wq : (seg == 1) ? wk : (seg == 2) ? wv : wo;
    bf16* dst = (seg < 3) ? (wqkv + (size_t)seg * DM * DM) : wob;
    const float4* p = reinterpret_cast<const float4*>(src) + (size_t)off * 2;
    float4 a = p[0], b = p[1];
    bf16x8 o;
    o[0] = (bf16)a.x; o[1] = (bf16)a.y; o[2] = (bf16)a.z; o[3] = (bf16)a.w;
    o[4] = (bf16)b.x; o[5] = (bf16)b.y; o[6] = (bf16)b.z; o[7] = (bf16)b.w;
    reinterpret_cast<bf16x8*>(dst)[off] = o;
}

// bias[b4][kt16][kg4][hi2][e16]: -inf where key padded, else 0.
// key = kt*128 + kg*32 + 4*hi + 8*(e>>2) + (e&3)
__global__ void biasprep_kernel(const int* __restrict__ mask, float* __restrict__ bias) {
    int idx = blockIdx.x * blockDim.x + threadIdx.x;
    if (idx >= 4 * 2048) return;
    int e = idx & 15, hi = (idx >> 4) & 1, kg = (idx >> 5) & 3;
    int kt = (idx >> 7) & 15, b = idx >> 11;
    int key = kt * 128 + kg * 32 + 4 * hi + 8 * (e >> 2) + (e & 3);
    bias[idx] = mask[b * SS + key] ? -__builtin_inff() : 0.f;
}

// C[M,N] = A[M,K](lda) * Bm[N,K]^T. 128x128 tile, BK=64, 4 waves, 16x16x32 MFMA.
template <typename OT>
__global__ __launch_bounds__(256) void gemm_bt(
    const bf16* __restrict__ A, int lda, const bf16* __restrict__ Bm, OT* __restrict__ C,
    int M, int N, int K)
{
    __shared__ bf16 As[128 * 64];
    __shared__ bf16 Bs[128 * 64];

    const int nwg = gridDim.x * gridDim.y;
    const int wg = blockIdx.y * gridDim.x + blockIdx.x;
    const int nsw = (wg & 7) * (nwg >> 3) + (wg >> 3);
    const int tn = nsw % gridDim.x, tm = nsw / gridDim.x;

    const int tid = threadIdx.x;
    const int lane = tid & 63, wv = tid >> 6;
    const int wr = wv >> 1, wc = wv & 1;
    const int lr = lane & 15, lg = lane >> 4;

    const f32x4 zero = {0.f, 0.f, 0.f, 0.f};
    f32x4 acc[4][4];
#pragma unroll
    for (int mi = 0; mi < 4; ++mi)
#pragma unroll
        for (int ni = 0; ni < 4; ++ni) acc[mi][ni] = zero;

    const char* Abase = (const char*)(A + (size_t)(tm * 128) * lda);
    const char* Bbase = (const char*)(Bm + (size_t)(tn * 128) * K);

    for (int k0 = 0; k0 < K; k0 += 64) {
#pragma unroll
        for (int i = 0; i < 4; ++i) {
            int idx = tid + 256 * i;
            int row = idx >> 3, ch = idx & 7;
            int gcol = (ch * 16) ^ ((row & 7) << 4);   // pre-swizzled source column
            gload_lds16(Abase + (size_t)row * (lda * 2) + k0 * 2 + gcol, (char*)As + idx * 16);
            gload_lds16(Bbase + (size_t)row * (K * 2) + k0 * 2 + gcol, (char*)Bs + idx * 16);
        }
        __syncthreads();

#pragma unroll
        for (int ks = 0; ks < 2; ++ks) {
            bf16x8 af[4], bfr[4];
#pragma unroll
            for (int mi = 0; mi < 4; ++mi) {
                int row = wr * 64 + mi * 16 + lr;
                af[mi] = *reinterpret_cast<const bf16x8*>(
                    (char*)As + swz(row, row * 128 + ks * 64 + lg * 16));
            }
#pragma unroll
            for (int ni = 0; ni < 4; ++ni) {
                int row = wc * 64 + ni * 16 + lr;
                bfr[ni] = *reinterpret_cast<const bf16x8*>(
                    (char*)Bs + swz(row, row * 128 + ks * 64 + lg * 16));
            }
#pragma unroll
            for (int mi = 0; mi < 4; ++mi)
#pragma unroll
                for (int ni = 0; ni < 4; ++ni)
                    acc[mi][ni] = __builtin_amdgcn_mfma_f32_16x16x32_bf16(
                        af[mi], bfr[ni], acc[mi][ni], 0, 0, 0);
        }
        __syncthreads();
    }

#pragma unroll
    for (int mi = 0; mi < 4; ++mi)
#pragma unroll
        for (int ni = 0; ni < 4; ++ni)
#pragma unroll
            for (int r = 0; r < 4; ++r) {
                int row = tm * 128 + wr * 64 + mi * 16 + lg * 4 + r;
                int col = tn * 128 + wc * 64 + ni * 16 + lr;
                C[(size_t)row * N + col] = (OT)acc[mi][ni][r];
            }
}

// Transpose V: vb[token][ldv] head-cols -> vT[(bh*64+d)][s]
__global__ __launch_bounds__(256) void vtrans_kernel(
    const bf16* __restrict__ vb, int ldv, bf16* __restrict__ vT)
{
    const int st = blockIdx.x, bh = blockIdx.y;
    const int b = bh >> 4, h = bh & 15;
    const int tid = threadIdx.x;
    __shared__ bf16 T[64 * 64];
#pragma unroll
    for (int i = 0; i < 2; ++i) {
        int idx = tid + 256 * i;
        int s = idx >> 3, ch = idx & 7;
        bf16x8 v = *reinterpret_cast<const bf16x8*>(
            vb + (size_t)(b * SS + st * 64 + s) * ldv + h * 64 + ch * 8);
        *reinterpret_cast<bf16x8*>((char*)T + swz(s, s * 128 + ch * 16)) = v;
    }
    __syncthreads();
#pragma unroll
    for (int i = 0; i < 2; ++i) {
        int idx = tid + 256 * i;
        int d = idx >> 3, ch = idx & 7;
        bf16x8 o;
#pragma unroll
        for (int j = 0; j < 8; ++j) {
            int s = ch * 8 + j;
            o[j] = *reinterpret_cast<const bf16*>((char*)T + swz(s, s * 128 + d * 2));
        }
        *reinterpret_cast<bf16x8*>(vT + ((size_t)bh * 64 + d) * SS + st * 64 + ch * 8) = o;
    }
}

// Flash attention: 8 waves x 32 q-rows, KVBLK=128, 16 iters, bias in LDS.
__global__ __launch_bounds__(512) void attn_kernel(
    const bf16* __restrict__ qkv, const bf16* __restrict__ vT,
    const float* __restrict__ bias, const int* __restrict__ mask,
    bf16* __restrict__ concat)
{
    // XCD-chunked swizzle over 512 blocks: each XCD owns 8 bh (L2-shared K/V)
    const int w = blockIdx.x;                 // 0..511
    const int nw = (w & 7) * 64 + (w >> 3);
    const int qt = nw & 7, bh = nw >> 3;      // qt 0..7, bh 0..63
    const int b = bh >> 4, h = bh & 15;
    const int tid = threadIdx.x;
    const int lane = tid & 63, wv = tid >> 6;
    const int lq = lane & 31, hi = lane >> 5;

    __shared__ bf16 Ks[2][128 * 64];    // [key][d]  rows 128B, swz (row&7)<<4
    __shared__ bf16 Vs[2][64 * 128];    // [d][key]  rows 256B, swz (row&15)<<4
    __shared__ float Bl[2048 + 16];     // bias slice (8KB) + 64B zero pad

    const size_t tok0 = (size_t)b * SS;
    const int qrow0 = qt * 256 + wv * 32;

    const int qpad = mask[tok0 + qrow0 + lq];
    bf16x8 qf[4];
    {
        const bf16* qp = qkv + (tok0 + qrow0 + lq) * QKVLD + h * 64 + hi * 8;
#pragma unroll
        for (int ks = 0; ks < 4; ++ks) {
            bf16x8 v = *reinterpret_cast<const bf16x8*>(qp + ks * 16);
#pragma unroll
            for (int j = 0; j < 8; ++j)
                v[j] = qpad ? (bf16)0.f : (bf16)((float)v[j] * LOG2E_DIV8);
            qf[ks] = v;
        }
    }

    float mrow = -3e38f, lrow = 0.f;
    f32x16 oA, oB;
#pragma unroll
    for (int e = 0; e < 16; ++e) { oA[e] = 0.f; oB[e] = 0.f; }

    // DMA staging geometry: K buf = 1024 chunks (128 rows x 8), V buf = 1024
    // chunks (64 rows x 16). Thread handles chunks c0=tid, c1=tid+512.
    const int c0 = tid, c1 = tid + 512;
    const int kr0 = c0 >> 3, kc0 = c0 & 7, kr1 = c1 >> 3, kc1 = c1 & 7;
    const int vr0 = c0 >> 4, vc0 = c0 & 15, vr1 = c1 >> 4, vc1 = c1 & 15;
    const char* kSrc = (const char*)(qkv + 1024 + h * 64);
    const char* vSrc = (const char*)(vT + (size_t)bh * 64 * SS);
    const size_t kOff0 = (tok0 + kr0) * (QKVLD * 2) + ((kc0 * 16) ^ ((kr0 & 7) << 4));
    const size_t kOff1 = (tok0 + kr1) * (QKVLD * 2) + ((kc1 * 16) ^ ((kr1 & 7) << 4));
    const size_t vOff0 = (size_t)vr0 * (SS * 2) + ((vc0 * 16) ^ ((vr0 & 15) << 4));
    const size_t vOff1 = (size_t)vr1 * (SS * 2) + ((vc1 * 16) ^ ((vr1 & 15) << 4));

    // LDS read constants
    const int kxor = (hi * 16) ^ ((lq & 7) << 4);     // K col xor
    const int vxor = (hi * 16) ^ ((lq & 15) << 4);    // V col xor
    const int bmask = qpad ? 0 : -1;                  // bias offset kill for padded q
    const char* bbase = (const char*)Bl + (qpad ? 8192 : hi * 64);

    // prologue: DMA tile 0 + bias slice; zero pad region
    gload_lds16(kSrc + kOff0, (char*)Ks[0] + c0 * 16);
    gload_lds16(kSrc + kOff1, (char*)Ks[0] + c1 * 16);
    gload_lds16(vSrc + vOff0, (char*)Vs[0] + c0 * 16);
    gload_lds16(vSrc + vOff1, (char*)Vs[0] + c1 * 16);
    gload_lds16((const char*)(bias + (size_t)b * 2048) + tid * 16, (char*)Bl + tid * 16);
    if (tid < 4) {
        f32x4 z = {0.f, 0.f, 0.f, 0.f};
        *reinterpret_cast<f32x4*>((char*)Bl + 8192 + tid * 16) = z;
    }
    __syncthreads();

    for (int kt = 0; kt < 16; ++kt) {
        const int cur = kt & 1;

        // (1) DMA next tile into other buffer (drained at end-of-iter barrier)
        if (kt < 15) {
            const size_t kAdv = (size_t)(kt + 1) * 128 * (QKVLD * 2);
            const size_t vAdv = (size_t)(kt + 1) * 256;
            gload_lds16(kSrc + kOff0 + kAdv, (char*)Ks[cur ^ 1] + c0 * 16);
            gload_lds16(kSrc + kOff1 + kAdv, (char*)Ks[cur ^ 1] + c1 * 16);
            gload_lds16(vSrc + vOff0 + vAdv, (char*)Vs[cur ^ 1] + c0 * 16);
            gload_lds16(vSrc + vOff1 + vAdv, (char*)Vs[cur ^ 1] + c1 * 16);
        }

        const char* kB = (const char*)Ks[cur];
        const char* vB = (const char*)Vs[cur];
        const int bo = (kt * 512) & bmask;

        // (2) QK^T: S^T[128 key][32 q], C-init = bias from LDS (broadcast reads)
        f32x16 s[4];
#pragma unroll
        for (int kg = 0; kg < 4; ++kg)
            s[kg] = *reinterpret_cast<const f32x16*>(bbase + bo + ((kg * 128) & bmask));
        __builtin_amdgcn_s_setprio(1);
#pragma unroll
        for (int kg = 0; kg < 4; ++kg) {
            const char* kR = kB + (kg * 32 + lq) * 128;
#pragma unroll
            for (int ks = 0; ks < 4; ++ks) {
                bf16x8 kf = *reinterpret_cast<const bf16x8*>(kR + (kxor ^ (ks * 32)));
                s[kg] = __builtin_amdgcn_mfma_f32_32x32x16_bf16(kf, qf[ks], s[kg], 0, 0, 0);
            }
        }
        __builtin_amdgcn_s_setprio(0);

        // (3) joint online softmax over 128 keys (log2 domain)
        float pm = fmaxf(s[0][0], s[0][1]);
#pragma unroll
        for (int kg = 0; kg < 4; ++kg)
#pragma unroll
            for (int e = (kg == 0 ? 2 : 0); e < 16; e += 2)
                pm = fmaxf(pm, fmaxf(s[kg][e], s[kg][e + 1]));
        pm = fmaxf(pm, __shfl_xor(pm, 32));

        if (!__all(pm <= mrow + 11.0f)) {   // T13 defer-max
            float mnew = fmaxf(mrow, pm);
            float scf = fexp2(mrow - mnew);
            mrow = mnew;
            lrow *= scf;
#pragma unroll
            for (int e = 0; e < 16; ++e) { oA[e] *= scf; oB[e] *= scf; }
        }

        float p[4][16];
        float ps0 = 0.f, ps1 = 0.f, ps2 = 0.f, ps3 = 0.f;
#pragma unroll
        for (int kg = 0; kg < 4; ++kg)
#pragma unroll
            for (int e = 0; e < 16; e += 4) {
                p[kg][e]     = fexp2(s[kg][e] - mrow);     ps0 += p[kg][e];
                p[kg][e + 1] = fexp2(s[kg][e + 1] - mrow); ps1 += p[kg][e + 1];
                p[kg][e + 2] = fexp2(s[kg][e + 2] - mrow); ps2 += p[kg][e + 2];
                p[kg][e + 3] = fexp2(s[kg][e + 3] - mrow); ps3 += p[kg][e + 3];
            }
        float psum = (ps0 + ps1) + (ps2 + ps3);
        psum += __shfl_xor(psum, 32);
        lrow += psum;

        // (4) PV: pack P -> bf16 B-fragments (cvt_pk + permlane32_swap), MFMA
        __builtin_amdgcn_s_setprio(1);
#pragma unroll
        for (int kk = 0; kk < 8; ++kk) {
            const float* pp = p[kk >> 1];
            const int ks2 = kk & 1;
            uint32_t c0p = cvtpk(pp[8 * ks2 + 0], pp[8 * ks2 + 1]);
            uint32_t c1p = cvtpk(pp[8 * ks2 + 2], pp[8 * ks2 + 3]);
            uint32_t c2p = cvtpk(pp[8 * ks2 + 4], pp[8 * ks2 + 5]);
            uint32_t c3p = cvtpk(pp[8 * ks2 + 6], pp[8 * ks2 + 7]);
            asm("v_permlane32_swap_b32 %0, %1" : "+v"(c0p), "+v"(c2p));
            asm("v_permlane32_swap_b32 %0, %1" : "+v"(c1p), "+v"(c3p));
            union { uint32_t u[4]; bf16x8 v; } pu;
            pu.u[0] = c0p; pu.u[1] = c1p; pu.u[2] = c2p; pu.u[3] = c3p;
            bf16x8 vf0 = *reinterpret_cast<const bf16x8*>(
                vB + (lq)*256 + (vxor ^ (kk * 32)));
            bf16x8 vf1 = *reinterpret_cast<const bf16x8*>(
                vB + (32 + lq) * 256 + (vxor ^ (kk * 32)));
            oA = __builtin_amdgcn_mfma_f32_32x32x16_bf16(vf0, pu.v, oA, 0, 0, 0);
            oB = __builtin_amdgcn_mfma_f32_32x32x16_bf16(vf1, pu.v, oB, 0, 0, 0);
        }
        __builtin_amdgcn_s_setprio(0);

        // (5) end-of-iter barrier drains the DMA (issued a full iter ago)
        if (kt < 15) __syncthreads();
    }

    // epilogue: O^T rows d = {0,32} + 4*hi + 8*g + r, col q = lane&31
    float inv = 1.0f / lrow;
#pragma unroll
    for (int g = 0; g < 4; ++g) {
        bf16x4 w0, w1;
#pragma unroll
        for (int r = 0; r < 4; ++r) {
            w0[r] = (bf16)(oA[g * 4 + r] * inv);
            w1[r] = (bf16)(oB[g * 4 + r] * inv);
        }
        int d0 = 4 * hi + 8 * g;
        bf16* cp = concat + (tok0 + qrow0 + lq) * QKVLD + h * 64 + d0;
        *reinterpret_cast<bf16x4*>(cp) = w0;
        *reinterpret_cast<bf16x4*>(cp + 32) = w1;
    }
}

extern "C" void kernel_launch(void* const* d_in, const int* in_sizes, int n_in,
                              void* d_out, int out_size, void* d_ws, size_t ws_size,
                              hipStream_t stream)
{
    const float* x  = (const float*)d_in[0];
    const int* mask = (const int*)d_in[1];
    const float* Wq = (const float*)d_in[2];
    const float* Wk = (const float*)d_in[3];
    const float* Wv = (const float*)d_in[4];
    const float* Wo = (const float*)d_in[5];
    float* out = (float*)d_out;

    // workspace (72 MiB):
    //  [0,16)  xb -> vT (xb dead after QKV gemm)
    //  [16,22) wqkv -> bias (dead after QKV gemm)   [22,24) wob
    //  [24,72) qkv [8192][3072]; v-cols (2048..3071) become concat after vtrans
    char* ws = (char*)d_ws;
    bf16* xb    = (bf16*)(ws);
    bf16* wqkv  = (bf16*)(ws + (16ull << 20));
    bf16* wob   = (bf16*)(ws + (22ull << 20));
    bf16* qkv   = (bf16*)(ws + (24ull << 20));
    bf16* vT    = xb;
    float* bias = (float*)wqkv;
    bf16* concat = qkv + 2048;   // strided [8192][.] within qkv, stride 3072

    cvt_kernel<<<dim3((NTOK * DM / 8) / 256), 256, 0, stream>>>(x, xb, NTOK * DM / 8);
    wcvt_kernel<<<dim3(2048), 256, 0, stream>>>(Wq, Wk, Wv, Wo, wqkv, wob);

    // fused QKV projection: qkv[8192,3072] = xb[8192,1024] @ wqkv[3072,1024]^T
    gemm_bt<bf16><<<dim3(QKVLD / 128, NTOK / 128), 256, 0, stream>>>(
        xb, DM, wqkv, qkv, NTOK, QKVLD, DM);

    vtrans_kernel<<<dim3(SS / 64, BB * NH), 256, 0, stream>>>(qkv + 2048, QKVLD, vT);
    biasprep_kernel<<<dim3(32), 256, 0, stream>>>(mask, bias);

    // (SS/256) q-tiles * (BB*NH) heads = 8 * 64 = 512 blocks of 512 threads
    attn_kernel<<<dim3((SS / 256) * (BB * NH)), 512, 0, stream>>>(
        qkv, vT, bias, mask, concat);

    // output projection: out = concat(lda=3072) @ wob^T
    gemm_bt<float><<<dim3(DM / 128, NTOK / 128), 256, 0, stream>>>(
        concat, QKVLD, wob, out, NTOK, DM, DM);
}

// Round 8
// 192.536 us; speedup vs baseline: 2.0789x; 1.0697x over previous
//
#include <hip/hip_runtime.h>
#include <stdint.h>

// MultiHeadAttention: B=4, S=2048, D_MODEL=1024, H=16, d_k=d_v=64
// Round 8: attn softmax de-VALU-ification. Fixed shift c=12 folded into the
// bias C-init (exact softmax, shift-invariant) -> p = v_exp_f32(s) directly:
// no fmax tree, no subtracts, no defer/rescale, no shfl. Row-sum computed on
// the matrix pipe via an all-ones A-fragment MFMA (lacc). Rest = round 7.

typedef __bf16 bf16;
typedef __bf16 bf16x8 __attribute__((ext_vector_type(8)));
typedef __bf16 bf16x4 __attribute__((ext_vector_type(4)));
typedef float f32x4 __attribute__((ext_vector_type(4)));
typedef float f32x16 __attribute__((ext_vector_type(16)));

#define DM    1024
#define NH    16
#define SS    2048
#define BB    4
#define NTOK  8192
#define QKVLD 3072
#define LOG2E_DIV8 0.18033688011112042f   // log2(e)/8: scale folded into Q, exp2 domain
#define CSHIFT 12.0f                      // fixed softmax shift (folded into bias)

__device__ __forceinline__ int swz(int row, int byteoff) {
    return byteoff ^ ((row & 7) << 4);
}
__device__ __forceinline__ float fexp2(float x) {
    float r; asm("v_exp_f32 %0, %1" : "=v"(r) : "v"(x)); return r;
}
__device__ __forceinline__ uint32_t cvtpk(float lo, float hi_) {
    uint32_t r; asm("v_cvt_pk_bf16_f32 %0, %1, %2" : "=v"(r) : "v"(lo), "v"(hi_)); return r;
}
__device__ __forceinline__ void gload_lds16(const void* g, void* l) {
    __builtin_amdgcn_global_load_lds(
        (const __attribute__((address_space(1))) uint32_t*)g,
        (__attribute__((address_space(3))) uint32_t*)l, 16, 0, 0);
}

__global__ void cvt_kernel(const float* __restrict__ in, bf16* __restrict__ out, int n8) {
    int i = blockIdx.x * blockDim.x + threadIdx.x;
    if (i >= n8) return;
    const float4* p = reinterpret_cast<const float4*>(in) + (size_t)i * 2;
    float4 a = p[0], b = p[1];
    bf16x8 o;
    o[0] = (bf16)a.x; o[1] = (bf16)a.y; o[2] = (bf16)a.z; o[3] = (bf16)a.w;
    o[4] = (bf16)b.x; o[5] = (bf16)b.y; o[6] = (bf16)b.z; o[7] = (bf16)b.w;
    reinterpret_cast<bf16x8*>(out)[i] = o;
}

// all 4 weight matrices (1M fp32 each) in one launch
__global__ void wcvt_kernel(const float* __restrict__ wq, const float* __restrict__ wk,
                            const float* __restrict__ wv, const float* __restrict__ wo,
                            bf16* __restrict__ wqkv, bf16* __restrict__ wob) {
    int i = blockIdx.x * blockDim.x + threadIdx.x;   // 8-elem group id, 4*131072 total
    int seg = i >> 17, off = i & 131071;
    const float* src = (seg == 0) ? wq : (seg == 1) ? wk : (seg == 2) ? wv : wo;
    bf16* dst = (seg < 3) ? (wqkv + (size_t)seg * DM * DM) : wob;
    const float4* p = reinterpret_cast<const float4*>(src) + (size_t)off * 2;
    float4 a = p[0], b = p[1];
    bf16x8 o;
    o[0] = (bf16)a.x; o[1] = (bf16)a.y; o[2] = (bf16)a.z; o[3] = (bf16)a.w;
    o[4] = (bf16)b.x; o[5] = (bf16)b.y; o[6] = (bf16)b.z; o[7] = (bf16)b.w;
    reinterpret_cast<bf16x8*>(dst)[off] = o;
}

// bias[b4][kt16][kg4][hi2][e16]: -inf where key padded, else -CSHIFT.
// key = kt*128 + kg*32 + 4*hi + 8*(e>>2) + (e&3)
__global__ void biasprep_kernel(const int* __restrict__ mask, float* __restrict__ bias) {
    int idx = blockIdx.x * blockDim.x + threadIdx.x;
    if (idx >= 4 * 2048) return;
    int e = idx & 15, hi = (idx >> 4) & 1, kg = (idx >> 5) & 3;
    int kt = (idx >> 7) & 15, b = idx >> 11;
    int key = kt * 128 + kg * 32 + 4 * hi + 8 * (e >> 2) + (e & 3);
    bias[idx] = mask[b * SS + key] ? -__builtin_inff() : -CSHIFT;
}

// C[M,N] = A[M,K](lda) * Bm[N,K]^T. 128x128 tile, BK=64, 4 waves, 16x16x32 MFMA.
template <typename OT>
__global__ __launch_bounds__(256) void gemm_bt(
    const bf16* __restrict__ A, int lda, const bf16* __restrict__ Bm, OT* __restrict__ C,
    int M, int N, int K)
{
    __shared__ bf16 As[128 * 64];
    __shared__ bf16 Bs[128 * 64];

    const int nwg = gridDim.x * gridDim.y;
    const int wg = blockIdx.y * gridDim.x + blockIdx.x;
    const int nsw = (wg & 7) * (nwg >> 3) + (wg >> 3);
    const int tn = nsw % gridDim.x, tm = nsw / gridDim.x;

    const int tid = threadIdx.x;
    const int lane = tid & 63, wv = tid >> 6;
    const int wr = wv >> 1, wc = wv & 1;
    const int lr = lane & 15, lg = lane >> 4;

    const f32x4 zero = {0.f, 0.f, 0.f, 0.f};
    f32x4 acc[4][4];
#pragma unroll
    for (int mi = 0; mi < 4; ++mi)
#pragma unroll
        for (int ni = 0; ni < 4; ++ni) acc[mi][ni] = zero;

    const char* Abase = (const char*)(A + (size_t)(tm * 128) * lda);
    const char* Bbase = (const char*)(Bm + (size_t)(tn * 128) * K);

    for (int k0 = 0; k0 < K; k0 += 64) {
#pragma unroll
        for (int i = 0; i < 4; ++i) {
            int idx = tid + 256 * i;
            int row = idx >> 3, ch = idx & 7;
            int gcol = (ch * 16) ^ ((row & 7) << 4);   // pre-swizzled source column
            gload_lds16(Abase + (size_t)row * (lda * 2) + k0 * 2 + gcol, (char*)As + idx * 16);
            gload_lds16(Bbase + (size_t)row * (K * 2) + k0 * 2 + gcol, (char*)Bs + idx * 16);
        }
        __syncthreads();

#pragma unroll
        for (int ks = 0; ks < 2; ++ks) {
            bf16x8 af[4], bfr[4];
#pragma unroll
            for (int mi = 0; mi < 4; ++mi) {
                int row = wr * 64 + mi * 16 + lr;
                af[mi] = *reinterpret_cast<const bf16x8*>(
                    (char*)As + swz(row, row * 128 + ks * 64 + lg * 16));
            }
#pragma unroll
            for (int ni = 0; ni < 4; ++ni) {
                int row = wc * 64 + ni * 16 + lr;
                bfr[ni] = *reinterpret_cast<const bf16x8*>(
                    (char*)Bs + swz(row, row * 128 + ks * 64 + lg * 16));
            }
#pragma unroll
            for (int mi = 0; mi < 4; ++mi)
#pragma unroll
                for (int ni = 0; ni < 4; ++ni)
                    acc[mi][ni] = __builtin_amdgcn_mfma_f32_16x16x32_bf16(
                        af[mi], bfr[ni], acc[mi][ni], 0, 0, 0);
        }
        __syncthreads();
    }

#pragma unroll
    for (int mi = 0; mi < 4; ++mi)
#pragma unroll
        for (int ni = 0; ni < 4; ++ni)
#pragma unroll
            for (int r = 0; r < 4; ++r) {
                int row = tm * 128 + wr * 64 + mi * 16 + lg * 4 + r;
                int col = tn * 128 + wc * 64 + ni * 16 + lr;
                C[(size_t)row * N + col] = (OT)acc[mi][ni][r];
            }
}

// Transpose V: vb[token][ldv] head-cols -> vT[(bh*64+d)][s]
__global__ __launch_bounds__(256) void vtrans_kernel(
    const bf16* __restrict__ vb, int ldv, bf16* __restrict__ vT)
{
    const int st = blockIdx.x, bh = blockIdx.y;
    const int b = bh >> 4, h = bh & 15;
    const int tid = threadIdx.x;
    __shared__ bf16 T[64 * 64];
#pragma unroll
    for (int i = 0; i < 2; ++i) {
        int idx = tid + 256 * i;
        int s = idx >> 3, ch = idx & 7;
        bf16x8 v = *reinterpret_cast<const bf16x8*>(
            vb + (size_t)(b * SS + st * 64 + s) * ldv + h * 64 + ch * 8);
        *reinterpret_cast<bf16x8*>((char*)T + swz(s, s * 128 + ch * 16)) = v;
    }
    __syncthreads();
#pragma unroll
    for (int i = 0; i < 2; ++i) {
        int idx = tid + 256 * i;
        int d = idx >> 3, ch = idx & 7;
        bf16x8 o;
#pragma unroll
        for (int j = 0; j < 8; ++j) {
            int s = ch * 8 + j;
            o[j] = *reinterpret_cast<const bf16*>((char*)T + swz(s, s * 128 + d * 2));
        }
        *reinterpret_cast<bf16x8*>(vT + ((size_t)bh * 64 + d) * SS + st * 64 + ch * 8) = o;
    }
}

// Flash attention: 8 waves x 32 q-rows, KVBLK=128, 16 iters, bias in LDS,
// fixed-shift softmax (no max tracking), row-sum via ones-MFMA.
__global__ __launch_bounds__(512) void attn_kernel(
    const bf16* __restrict__ qkv, const bf16* __restrict__ vT,
    const float* __restrict__ bias, const int* __restrict__ mask,
    bf16* __restrict__ concat)
{
    // XCD-chunked swizzle over 512 blocks: each XCD owns 8 bh (L2-shared K/V)
    const int w = blockIdx.x;                 // 0..511
    const int nw = (w & 7) * 64 + (w >> 3);
    const int qt = nw & 7, bh = nw >> 3;      // qt 0..7, bh 0..63
    const int b = bh >> 4, h = bh & 15;
    const int tid = threadIdx.x;
    const int lane = tid & 63, wv = tid >> 6;
    const int lq = lane & 31, hi = lane >> 5;

    __shared__ bf16 Ks[2][128 * 64];    // [key][d]  rows 128B, swz (row&7)<<4
    __shared__ bf16 Vs[2][64 * 128];    // [d][key]  rows 256B, swz (row&15)<<4
    __shared__ float Bl[2048 + 16];     // bias slice (8KB) + 64B const pad (-CSHIFT)

    const size_t tok0 = (size_t)b * SS;
    const int qrow0 = qt * 256 + wv * 32;

    const int qpad = mask[tok0 + qrow0 + lq];
    bf16x8 qf[4];
    {
        const bf16* qp = qkv + (tok0 + qrow0 + lq) * QKVLD + h * 64 + hi * 8;
#pragma unroll
        for (int ks = 0; ks < 4; ++ks) {
            bf16x8 v = *reinterpret_cast<const bf16x8*>(qp + ks * 16);
#pragma unroll
            for (int j = 0; j < 8; ++j)
                v[j] = qpad ? (bf16)0.f : (bf16)((float)v[j] * LOG2E_DIV8);
            qf[ks] = v;
        }
    }
    // all-ones A-fragment for the row-sum MFMA
    bf16x8 ones;
#pragma unroll
    for (int j = 0; j < 8; ++j) ones[j] = (bf16)1.0f;

    f32x16 oA, oB, lacc;
#pragma unroll
    for (int e = 0; e < 16; ++e) { oA[e] = 0.f; oB[e] = 0.f; lacc[e] = 0.f; }

    // DMA staging geometry: K buf = 1024 chunks (128 rows x 8), V buf = 1024
    // chunks (64 rows x 16). Thread handles chunks c0=tid, c1=tid+512.
    const int c0 = tid, c1 = tid + 512;
    const int kr0 = c0 >> 3, kc0 = c0 & 7, kr1 = c1 >> 3, kc1 = c1 & 7;
    const int vr0 = c0 >> 4, vc0 = c0 & 15, vr1 = c1 >> 4, vc1 = c1 & 15;
    const char* kSrc = (const char*)(qkv + 1024 + h * 64);
    const char* vSrc = (const char*)(vT + (size_t)bh * 64 * SS);
    const size_t kOff0 = (tok0 + kr0) * (QKVLD * 2) + ((kc0 * 16) ^ ((kr0 & 7) << 4));
    const size_t kOff1 = (tok0 + kr1) * (QKVLD * 2) + ((kc1 * 16) ^ ((kr1 & 7) << 4));
    const size_t vOff0 = (size_t)vr0 * (SS * 2) + ((vc0 * 16) ^ ((vr0 & 15) << 4));
    const size_t vOff1 = (size_t)vr1 * (SS * 2) + ((vc1 * 16) ^ ((vr1 & 15) << 4));

    // LDS read constants
    const int kxor = (hi * 16) ^ ((lq & 7) << 4);     // K col xor
    const int vxor = (hi * 16) ^ ((lq & 15) << 4);    // V col xor
    const int bmask = qpad ? 0 : -1;                  // bias offset kill for padded q
    const char* bbase = (const char*)Bl + (qpad ? 8192 : hi * 64);

    // prologue: DMA tile 0 + bias slice; fill const pad region with -CSHIFT
    gload_lds16(kSrc + kOff0, (char*)Ks[0] + c0 * 16);
    gload_lds16(kSrc + kOff1, (char*)Ks[0] + c1 * 16);
    gload_lds16(vSrc + vOff0, (char*)Vs[0] + c0 * 16);
    gload_lds16(vSrc + vOff1, (char*)Vs[0] + c1 * 16);
    gload_lds16((const char*)(bias + (size_t)b * 2048) + tid * 16, (char*)Bl + tid * 16);
    if (tid < 4) {
        f32x4 z = {-CSHIFT, -CSHIFT, -CSHIFT, -CSHIFT};
        *reinterpret_cast<f32x4*>((char*)Bl + 8192 + tid * 16) = z;
    }
    __syncthreads();

    for (int kt = 0; kt < 16; ++kt) {
        const int cur = kt & 1;

        // (1) DMA next tile into other buffer (drained at end-of-iter barrier)
        if (kt < 15) {
            const size_t kAdv = (size_t)(kt + 1) * 128 * (QKVLD * 2);
            const size_t vAdv = (size_t)(kt + 1) * 256;
            gload_lds16(kSrc + kOff0 + kAdv, (char*)Ks[cur ^ 1] + c0 * 16);
            gload_lds16(kSrc + kOff1 + kAdv, (char*)Ks[cur ^ 1] + c1 * 16);
            gload_lds16(vSrc + vOff0 + vAdv, (char*)Vs[cur ^ 1] + c0 * 16);
            gload_lds16(vSrc + vOff1 + vAdv, (char*)Vs[cur ^ 1] + c1 * 16);
        }

        const char* kB = (const char*)Ks[cur];
        const char* vB = (const char*)Vs[cur];
        const int bo = (kt * 512) & bmask;

        // (2) QK^T: S^T[128 key][32 q], C-init = bias-with-shift from LDS
        f32x16 s[4];
#pragma unroll
        for (int kg = 0; kg < 4; ++kg)
            s[kg] = *reinterpret_cast<const f32x16*>(bbase + bo + ((kg * 128) & bmask));
        __builtin_amdgcn_s_setprio(1);
#pragma unroll
        for (int kg = 0; kg < 4; ++kg) {
            const char* kR = kB + (kg * 32 + lq) * 128;
#pragma unroll
            for (int ks = 0; ks < 4; ++ks) {
                bf16x8 kf = *reinterpret_cast<const bf16x8*>(kR + (kxor ^ (ks * 32)));
                s[kg] = __builtin_amdgcn_mfma_f32_32x32x16_bf16(kf, qf[ks], s[kg], 0, 0, 0);
            }
        }
        __builtin_amdgcn_s_setprio(0);

        // (3) p = exp2(s) in place — no max, no subtract (shift lives in bias)
#pragma unroll
        for (int kg = 0; kg < 4; ++kg)
#pragma unroll
            for (int e = 0; e < 16; ++e)
                s[kg][e] = fexp2(s[kg][e]);

        // (4) pack P -> bf16 B-fragments; PV MFMA + row-sum via ones-MFMA
        __builtin_amdgcn_s_setprio(1);
#pragma unroll
        for (int kk = 0; kk < 8; ++kk) {
            const float* pp = (const float*)&s[kk >> 1];
            const int ks2 = kk & 1;
            uint32_t c0p = cvtpk(pp[8 * ks2 + 0], pp[8 * ks2 + 1]);
            uint32_t c1p = cvtpk(pp[8 * ks2 + 2], pp[8 * ks2 + 3]);
            uint32_t c2p = cvtpk(pp[8 * ks2 + 4], pp[8 * ks2 + 5]);
            uint32_t c3p = cvtpk(pp[8 * ks2 + 6], pp[8 * ks2 + 7]);
            asm("v_permlane32_swap_b32 %0, %1" : "+v"(c0p), "+v"(c2p));
            asm("v_permlane32_swap_b32 %0, %1" : "+v"(c1p), "+v"(c3p));
            union { uint32_t u[4]; bf16x8 v; } pu;
            pu.u[0] = c0p; pu.u[1] = c1p; pu.u[2] = c2p; pu.u[3] = c3p;
            bf16x8 vf0 = *reinterpret_cast<const bf16x8*>(
                vB + (lq)*256 + (vxor ^ (kk * 32)));
            bf16x8 vf1 = *reinterpret_cast<const bf16x8*>(
                vB + (32 + lq) * 256 + (vxor ^ (kk * 32)));
            oA = __builtin_amdgcn_mfma_f32_32x32x16_bf16(vf0, pu.v, oA, 0, 0, 0);
            oB = __builtin_amdgcn_mfma_f32_32x32x16_bf16(vf1, pu.v, oB, 0, 0, 0);
            lacc = __builtin_amdgcn_mfma_f32_32x32x16_bf16(ones, pu.v, lacc, 0, 0, 0);
        }
        __builtin_amdgcn_s_setprio(0);

        // (5) end-of-iter barrier drains the DMA (issued a full iter ago)
        if (kt < 15) __syncthreads();
    }

    // epilogue: O^T rows d = {0,32} + 4*hi + 8*g + r, col q = lane&31.
    // lacc rows are all identical (= sum of p over all keys) -> use lacc[0].
    float inv = 1.0f / lacc[0];
#pragma unroll
    for (int g = 0; g < 4; ++g) {
        bf16x4 w0, w1;
#pragma unroll
        for (int r = 0; r < 4; ++r) {
            w0[r] = (bf16)(oA[g * 4 + r] * inv);
            w1[r] = (bf16)(oB[g * 4 + r] * inv);
        }
        int d0 = 4 * hi + 8 * g;
        bf16* cp = concat + (tok0 + qrow0 + lq) * QKVLD + h * 64 + d0;
        *reinterpret_cast<bf16x4*>(cp) = w0;
        *reinterpret_cast<bf16x4*>(cp + 32) = w1;
    }
}

extern "C" void kernel_launch(void* const* d_in, const int* in_sizes, int n_in,
                              void* d_out, int out_size, void* d_ws, size_t ws_size,
                              hipStream_t stream)
{
    const float* x  = (const float*)d_in[0];
    const int* mask = (const int*)d_in[1];
    const float* Wq = (const float*)d_in[2];
    const float* Wk = (const float*)d_in[3];
    const float* Wv = (const float*)d_in[4];
    const float* Wo = (const float*)d_in[5];
    float* out = (float*)d_out;

    // workspace (72 MiB):
    //  [0,16)  xb -> vT (xb dead after QKV gemm)
    //  [16,22) wqkv -> bias (dead after QKV gemm)   [22,24) wob
    //  [24,72) qkv [8192][3072]; v-cols (2048..3071) become concat after vtrans
    char* ws = (char*)d_ws;
    bf16* xb    = (bf16*)(ws);
    bf16* wqkv  = (bf16*)(ws + (16ull << 20));
    bf16* wob   = (bf16*)(ws + (22ull << 20));
    bf16* qkv   = (bf16*)(ws + (24ull << 20));
    bf16* vT    = xb;
    float* bias = (float*)wqkv;
    bf16* concat = qkv + 2048;   // strided [8192][.] within qkv, stride 3072

    cvt_kernel<<<dim3((NTOK * DM / 8) / 256), 256, 0, stream>>>(x, xb, NTOK * DM / 8);
    wcvt_kernel<<<dim3(2048), 256, 0, stream>>>(Wq, Wk, Wv, Wo, wqkv, wob);

    // fused QKV projection: qkv[8192,3072] = xb[8192,1024] @ wqkv[3072,1024]^T
    gemm_bt<bf16><<<dim3(QKVLD / 128, NTOK / 128), 256, 0, stream>>>(
        xb, DM, wqkv, qkv, NTOK, QKVLD, DM);

    vtrans_kernel<<<dim3(SS / 64, BB * NH), 256, 0, stream>>>(qkv + 2048, QKVLD, vT);
    biasprep_kernel<<<dim3(32), 256, 0, stream>>>(mask, bias);

    // (SS/256) q-tiles * (BB*NH) heads = 8 * 64 = 512 blocks of 512 threads
    attn_kernel<<<dim3((SS / 256) * (BB * NH)), 512, 0, stream>>>(
        qkv, vT, bias, mask, concat);

    // output projection: out = concat(lda=3072) @ wob^T
    gemm_bt<float><<<dim3(DM / 128, NTOK / 128), 256, 0, stream>>>(
        concat, QKVLD, wob, out, NTOK, DM, DM);
}